// Round 9
// baseline (881.020 us; speedup 1.0000x reference)
//
#include <hip/hip_runtime.h>
#include <math.h>

#define NTOK   256000
#define TOKB   16000
#define EPS    1e-5f

__device__ __forceinline__ float gelu_f(float x){
  return 0.5f*x*(1.0f+erff(x*0.70710678118654752440f));
}
__device__ __forceinline__ float elu1_f(float x){
  return x>0.0f ? x+1.0f : __expf(x);   // elu(x)+1
}
// read lane l's copy of x (l uniform): v_readlane_b32 -> SGPR, no DS traffic
__device__ __forceinline__ float rl(float x, int l){
  return __int_as_float(__builtin_amdgcn_readlane(__float_as_int(x), l));
}

// ---------------------------------------------------------------------------
// One-shot prep: transpose proj_mat -> pmT [l][h][f][d], w1 -> w1T [l][j][i]
// ---------------------------------------------------------------------------
__global__ __launch_bounds__(256) void k_prep(
    const float* __restrict__ proj_mat, const float* __restrict__ w1,
    float* __restrict__ pmT, float* __restrict__ w1T)
{
  const int i = blockIdx.x*256 + threadIdx.x;
  if (i < 4096){
    const int l=i>>11, h=(i>>9)&3, f=(i>>3)&63, d=i&7;
    pmT[i] = proj_mat[l*2048 + h*512 + d*64 + f];
    const int j=(i>>5)&63, i2=i&31;
    w1T[i] = w1[l*2048 + i2*64 + j];
  }
}

// ---------------------------------------------------------------------------
// Tokenizer: band conv(51) -> 1x1 conv(4->32) -> BN -> GELU -> avgpool(4)
// ---------------------------------------------------------------------------
__global__ __launch_bounds__(256) void k_tokenize(
    const float* __restrict__ x, const float* __restrict__ band_w,
    const float* __restrict__ pw_w, const float* __restrict__ bn_g,
    const float* __restrict__ bn_b, const float* __restrict__ bn_m,
    const float* __restrict__ bn_v, float* __restrict__ hout)
{
  __shared__ float sx[1050];
  __shared__ float sbw[4][51];
  __shared__ float spw[32][4];
  __shared__ float sscale[32], sshift[32];
  const int tid = threadIdx.x;
  const int b = blockIdx.x >> 6, e = blockIdx.x & 63;
  const float* xr = x + (size_t)(b*64 + e)*1000;
  for (int i=tid;i<1050;i+=256){ int t=i-25; sx[i]=(t>=0&&t<1000)?xr[t]:0.0f; }
  for (int i=tid;i<204;i+=256){ sbw[i/51][i%51] = band_w[i]; }
  for (int i=tid;i<128;i+=256){ spw[i>>2][i&3] = pw_w[i]; }
  if (tid<32){ float sc = bn_g[tid]*rsqrtf(bn_v[tid]+EPS);
               sscale[tid]=sc; sshift[tid]=bn_b[tid]-bn_m[tid]*sc; }
  __syncthreads();
  const int tp = tid;
  if (tp < 250) {
    float acc[32];
    #pragma unroll
    for (int o=0;o<32;o++) acc[o]=0.0f;
    for (int j=0;j<4;j++){
      const int t = 4*tp+j;
      float c0=0,c1=0,c2=0,c3=0;
      for (int k=0;k<51;k++){
        float xv = sx[t+k];
        c0 += xv*sbw[0][k]; c1 += xv*sbw[1][k];
        c2 += xv*sbw[2][k]; c3 += xv*sbw[3][k];
      }
      #pragma unroll
      for (int o=0;o<32;o++){
        float hv = spw[o][0]*c0 + spw[o][1]*c1 + spw[o][2]*c2 + spw[o][3]*c3;
        hv = hv*sscale[o] + sshift[o];
        acc[o] += gelu_f(hv);
      }
    }
    const int tok = b*TOKB + e*250 + tp;
    float4* dst = (float4*)(hout + (size_t)tok*32);
    #pragma unroll
    for (int o8=0;o8<8;o8++)
      dst[o8] = make_float4(acc[o8*4]*0.25f, acc[o8*4+1]*0.25f,
                            acc[o8*4+2]*0.25f, acc[o8*4+3]*0.25f);
  }
}

// ---------------------------------------------------------------------------
// Pass A: per 128-token tile: ln1 -> k,v (LDS swkT) -> phase2 via readlane
// ---------------------------------------------------------------------------
__global__ __launch_bounds__(256) void k_kv_partial(
    const float* __restrict__ hbuf, const float* __restrict__ lg,
    const float* __restrict__ lb, const float* __restrict__ W,   // wqkv + l*3072
    const float* __restrict__ pm,                                // proj_mat + l*2048
    float* __restrict__ kvpart)
{
  __shared__ __align__(16) float sk[128][36];
  __shared__ __align__(16) float sv[128][36];
  __shared__ __align__(16) float swkT[64][32];   // [j][i]: j<32 k-cols, j>=32 v-cols
  const int tid = threadIdx.x;
  for (int idx=tid;idx<2048;idx+=256){
    int i = idx&31, j = idx>>5;
    swkT[j][i] = W[i*96 + 32 + j];
  }
  __syncthreads();
  {
    const int tloc = tid>>1, half = tid&1;
    const int tok = blockIdx.x*128 + tloc;
    float hx[32];
    const float4* src = (const float4*)(hbuf + (size_t)tok*32);
    #pragma unroll
    for (int i=0;i<8;i++){ float4 v4=src[i]; hx[4*i]=v4.x; hx[4*i+1]=v4.y; hx[4*i+2]=v4.z; hx[4*i+3]=v4.w; }
    float mu=0;
    #pragma unroll
    for (int i=0;i<32;i++) mu += hx[i];
    mu *= (1.0f/32.0f);
    float vs=0;
    #pragma unroll
    for (int i=0;i<32;i++){ float d=hx[i]-mu; vs += d*d; }
    const float inv = rsqrtf(vs*(1.0f/32.0f)+EPS);
    float xn[32];
    #pragma unroll
    for (int i=0;i<32;i++) xn[i] = (hx[i]-mu)*inv*lg[i]+lb[i];
    const int j0 = half*16;
    #pragma unroll 4
    for (int jj=0;jj<16;jj++){
      const int j = j0+jj;
      const float4* wk4 = (const float4*)&swkT[j][0];
      const float4* wv4 = (const float4*)&swkT[32+j][0];
      float ka=0, va=0;
      #pragma unroll
      for (int i4=0;i4<8;i4++){
        float4 wk = wk4[i4], wv = wv4[i4];
        ka += xn[4*i4+0]*wk.x + xn[4*i4+1]*wk.y + xn[4*i4+2]*wk.z + xn[4*i4+3]*wk.w;
        va += xn[4*i4+0]*wv.x + xn[4*i4+1]*wv.y + xn[4*i4+2]*wv.z + xn[4*i4+3]*wv.w;
      }
      sk[tloc][j]=ka; sv[tloc][j]=va;
    }
  }
  __syncthreads();
  // phase 2: wave hh handles head hh; lane f; k/v distributed into registers
  const int hh = tid>>6, f = tid&63;
  float pm0,pm1,pm2,pm3,pm4,pm5,pm6,pm7;
  {
    const float* pmp = pm + (size_t)hh*512 + f;
    pm0=pmp[0]; pm1=pmp[64]; pm2=pmp[128]; pm3=pmp[192];
    pm4=pmp[256]; pm5=pmp[320]; pm6=pmp[384]; pm7=pmp[448];
  }
  float4 kA0,kB0,kA1,kB1,vA0,vB0,vA1,vB1;
  {
    const float4* p0 = (const float4*)&sk[f][hh*8];       kA0=p0[0]; kB0=p0[1];
    const float4* p1 = (const float4*)&sk[64+f][hh*8];    kA1=p1[0]; kB1=p1[1];
    const float4* p2 = (const float4*)&sv[f][hh*8];       vA0=p2[0]; vB0=p2[1];
    const float4* p3 = (const float4*)&sv[64+f][hh*8];    vA1=p3[0]; vB1=p3[1];
  }
  float a0=0,a1=0,a2=0,a3=0,a4=0,a5=0,a6=0,a7=0;
  #pragma unroll 2
  for (int t=0;t<64;t++){
    float kd = rl(kA0.x,t)*pm0 + rl(kA0.y,t)*pm1 + rl(kA0.z,t)*pm2 + rl(kA0.w,t)*pm3
             + rl(kB0.x,t)*pm4 + rl(kB0.y,t)*pm5 + rl(kB0.z,t)*pm6 + rl(kB0.w,t)*pm7;
    const float Kf = elu1_f(kd);
    a0 += Kf*rl(vA0.x,t); a1 += Kf*rl(vA0.y,t); a2 += Kf*rl(vA0.z,t); a3 += Kf*rl(vA0.w,t);
    a4 += Kf*rl(vB0.x,t); a5 += Kf*rl(vB0.y,t); a6 += Kf*rl(vB0.z,t); a7 += Kf*rl(vB0.w,t);
  }
  #pragma unroll 2
  for (int t=0;t<64;t++){
    float kd = rl(kA1.x,t)*pm0 + rl(kA1.y,t)*pm1 + rl(kA1.z,t)*pm2 + rl(kA1.w,t)*pm3
             + rl(kB1.x,t)*pm4 + rl(kB1.y,t)*pm5 + rl(kB1.z,t)*pm6 + rl(kB1.w,t)*pm7;
    const float Kf = elu1_f(kd);
    a0 += Kf*rl(vA1.x,t); a1 += Kf*rl(vA1.y,t); a2 += Kf*rl(vA1.z,t); a3 += Kf*rl(vA1.w,t);
    a4 += Kf*rl(vB1.x,t); a5 += Kf*rl(vB1.y,t); a6 += Kf*rl(vB1.z,t); a7 += Kf*rl(vB1.w,t);
  }
  float4* dst = (float4*)(kvpart + (size_t)blockIdx.x*2048 + tid*8);
  dst[0] = make_float4(a0,a1,a2,a3);
  dst[1] = make_float4(a4,a5,a6,a7);
}

// fixed-order hierarchical KV reduction: 2000 partials -> 10 chunks -> final
__global__ __launch_bounds__(256) void k_kv_reduce1(
    const float* __restrict__ kvpart, float* __restrict__ p2)
{
  const int chunk = blockIdx.x >> 3;                 // 0..9
  const int e = (blockIdx.x&7)*256 + threadIdx.x;    // 0..2047
  float acc=0.0f;
  const int base = chunk*200;
  for (int ab=0; ab<200; ab++) acc += kvpart[(size_t)(base+ab)*2048 + e];
  p2[chunk*2048 + e] = acc;
}

__global__ __launch_bounds__(256) void k_kv_reduce2(
    const float* __restrict__ p2, float* __restrict__ KV)
{
  const int hf = threadIdx.x;
  float acc[8];
  #pragma unroll
  for (int d=0;d<8;d++) acc[d]=0.0f;
  for (int c=0;c<10;c++){
    #pragma unroll
    for (int d=0;d<8;d++) acc[d] += p2[c*2048 + hf*8 + d];
  }
  #pragma unroll
  for (int d=0;d<8;d++) KV[hf*8+d]=acc[d];
}

// ---------------------------------------------------------------------------
// Pass C1 (thread-per-token): q/proj via LDS broadcast (512 DS/wave);
// the dominant f-loop via distributed VGPRs + v_readlane (0 DS).
// ---------------------------------------------------------------------------
__global__ __launch_bounds__(256) void k_attn(
    float* __restrict__ hbuf,
    const float* __restrict__ lg, const float* __restrict__ lb,
    const float* __restrict__ wq,      // wqkv + l*3072 (q cols 0..31)
    const float* __restrict__ pmT,     // ws pmT + l*2048 : [h][f][d]
    const float* __restrict__ wp,      // wproj + l*1024
    const float* __restrict__ bp,      // bproj + l*32
    const float* __restrict__ KV)      // [h*64+f][d]
{
  __shared__ __align__(16) float swqT[32][32];   // [j][i]
  __shared__ __align__(16) float swpT[32][32];   // [o][i]
  __shared__ float s1g[32], s1b[32], sbp[32];
  const int tid = threadIdx.x;
  for (int idx=tid; idx<1024; idx+=256){
    int j=idx>>5, i=idx&31;
    swqT[j][i] = wq[i*96+j];
    swpT[j][i] = wp[i*32+j];
  }
  if (tid<32){ s1g[tid]=lg[tid]; s1b[tid]=lb[tid]; sbp[tid]=bp[tid]; }
  __syncthreads();

  const int lane = tid & 63;
  const int tok = blockIdx.x*256 + tid;
  float4* hp = (float4*)(hbuf + (size_t)tok*32);

  // ---- ln1 (lane-local) ----
  float xn[32];
  {
    float hx[32];
    #pragma unroll
    for (int i=0;i<8;i++){ float4 v=hp[i]; hx[4*i]=v.x; hx[4*i+1]=v.y; hx[4*i+2]=v.z; hx[4*i+3]=v.w; }
    float mu=0;
    #pragma unroll
    for (int i=0;i<32;i++) mu += hx[i];
    mu *= (1.0f/32.0f);
    float vs=0;
    #pragma unroll
    for (int i=0;i<32;i++){ float d=hx[i]-mu; vs += d*d; }
    const float inv = rsqrtf(vs*(1.0f/32.0f)+EPS);
    #pragma unroll
    for (int i=0;i<32;i++) xn[i] = (hx[i]-mu)*inv*s1g[i]+s1b[i];
  }

  float att[32];
  #pragma unroll
  for (int hh=0;hh<4;hh++){
    // q slice (LDS broadcast rows)
    float qh[8];
    #pragma unroll
    for (int d=0;d<8;d++){
      const float4* wr = (const float4*)&swqT[hh*8+d][0];
      float a=0;
      #pragma unroll
      for (int i4=0;i4<8;i4++){
        float4 w = wr[i4];
        a += xn[4*i4+0]*w.x + xn[4*i4+1]*w.y + xn[4*i4+2]*w.z + xn[4*i4+3]*w.w;
      }
      qh[d]=a;
    }
    // distributed pm/kv for this head: lane f holds pmT[h][f][:], KV[h][f][:]
    const float4* pmb = (const float4*)(pmT + hh*512 + lane*8);
    float4 pA = pmb[0], pB = pmb[1];
    const float4* kvb = (const float4*)(KV + hh*512 + lane*8);
    float4 kA = kvb[0], kB = kvb[1];
    float a0=0,a1=0,a2=0,a3=0,a4=0,a5=0,a6=0,a7=0;
    #pragma unroll 4
    for (int f=0; f<64; f++){
      float qd = qh[0]*rl(pA.x,f)+qh[1]*rl(pA.y,f)+qh[2]*rl(pA.z,f)+qh[3]*rl(pA.w,f)
               + qh[4]*rl(pB.x,f)+qh[5]*rl(pB.y,f)+qh[6]*rl(pB.z,f)+qh[7]*rl(pB.w,f);
      const float Qf = elu1_f(qd);
      a0+=Qf*rl(kA.x,f); a1+=Qf*rl(kA.y,f); a2+=Qf*rl(kA.z,f); a3+=Qf*rl(kA.w,f);
      a4+=Qf*rl(kB.x,f); a5+=Qf*rl(kB.y,f); a6+=Qf*rl(kB.z,f); a7+=Qf*rl(kB.w,f);
    }
    const float den = a0+a1+a2+a3+a4+a5+a6+a7;
    const float z = 1.0f/den;
    att[hh*8+0]=a0*z; att[hh*8+1]=a1*z; att[hh*8+2]=a2*z; att[hh*8+3]=a3*z;
    att[hh*8+4]=a4*z; att[hh*8+5]=a5*z; att[hh*8+6]=a6*z; att[hh*8+7]=a7*z;
  }

  // ---- proj + residual (LDS broadcast rows) ----
  #pragma unroll
  for (int o4=0;o4<8;o4++){
    float p0=sbp[4*o4+0], p1=sbp[4*o4+1], p2=sbp[4*o4+2], p3=sbp[4*o4+3];
    const float4* w0 = (const float4*)&swpT[o4*4+0][0];
    const float4* w1r= (const float4*)&swpT[o4*4+1][0];
    const float4* w2r= (const float4*)&swpT[o4*4+2][0];
    const float4* w3 = (const float4*)&swpT[o4*4+3][0];
    #pragma unroll
    for (int i4=0;i4<8;i4++){
      float4 b0=w0[i4], b1=w1r[i4], b2=w2r[i4], b3=w3[i4];
      p0 += att[4*i4+0]*b0.x + att[4*i4+1]*b0.y + att[4*i4+2]*b0.z + att[4*i4+3]*b0.w;
      p1 += att[4*i4+0]*b1.x + att[4*i4+1]*b1.y + att[4*i4+2]*b1.z + att[4*i4+3]*b1.w;
      p2 += att[4*i4+0]*b2.x + att[4*i4+1]*b2.y + att[4*i4+2]*b2.z + att[4*i4+3]*b2.w;
      p3 += att[4*i4+0]*b3.x + att[4*i4+1]*b3.y + att[4*i4+2]*b3.z + att[4*i4+3]*b3.w;
    }
    float4 hx4 = hp[o4];
    hp[o4] = make_float4(hx4.x+p0, hx4.y+p1, hx4.z+p2, hx4.w+p3);
  }
}

// ---------------------------------------------------------------------------
// Pass C2 (thread-per-token, ZERO LDS): ln2 -> FFN -> residual.
// W1/W2/b1 distributed across lanes (lane j holds row j); j-loop readlane.
// ---------------------------------------------------------------------------
__global__ __launch_bounds__(256) void k_ffn(
    float* __restrict__ hbuf,
    const float* __restrict__ lg, const float* __restrict__ lb,
    const float* __restrict__ w1T,     // ws w1T + l*2048 : [j][i]
    const float* __restrict__ b1,      // b1 + l*64
    const float* __restrict__ w2,      // w2 + l*2048 : [j][c]
    const float* __restrict__ b2)      // b2 + l*32
{
  const int tid = threadIdx.x;
  const int lane = tid & 63;
  const int tok = blockIdx.x*256 + tid;
  float4* hp = (float4*)(hbuf + (size_t)tok*32);

  // distributed weights: lane j holds w1T[j][0..31], w2[j][0..31], b1[j]
  float W1r[32], W2r[32];
  {
    const float4* r1 = (const float4*)(w1T + lane*32);
    const float4* r2 = (const float4*)(w2  + lane*32);
    #pragma unroll
    for (int k=0;k<8;k++){
      float4 a=r1[k]; W1r[4*k]=a.x; W1r[4*k+1]=a.y; W1r[4*k+2]=a.z; W1r[4*k+3]=a.w;
      float4 b=r2[k]; W2r[4*k]=b.x; W2r[4*k+1]=b.y; W2r[4*k+2]=b.z; W2r[4*k+3]=b.w;
    }
  }
  const float myb1 = b1[lane];

  // ---- ln2 ----
  float m[32];
  {
    float hx[32];
    #pragma unroll
    for (int i=0;i<8;i++){ float4 v=hp[i]; hx[4*i]=v.x; hx[4*i+1]=v.y; hx[4*i+2]=v.z; hx[4*i+3]=v.w; }
    float mu=0;
    #pragma unroll
    for (int i=0;i<32;i++) mu += hx[i];
    mu *= (1.0f/32.0f);
    float vs=0;
    #pragma unroll
    for (int i=0;i<32;i++){ float d=hx[i]-mu; vs += d*d; }
    const float inv = rsqrtf(vs*(1.0f/32.0f)+EPS);
    #pragma unroll
    for (int i=0;i<32;i++) m[i] = (hx[i]-mu)*inv*lg[i]+lb[i];
  }

  float f[32];
  #pragma unroll
  for (int c=0;c<32;c++) f[c] = b2[c];

  #pragma unroll 2
  for (int j=0;j<64;j++){
    float g = rl(myb1, j);
    #pragma unroll
    for (int i=0;i<32;i++) g += m[i]*rl(W1r[i], j);
    const float gg = gelu_f(g);
    #pragma unroll
    for (int c=0;c<32;c++) f[c] += gg*rl(W2r[c], j);
  }

  #pragma unroll
  for (int o4=0;o4<8;o4++){
    float4 hx4 = hp[o4];
    hp[o4] = make_float4(hx4.x+f[4*o4+0], hx4.y+f[4*o4+1],
                         hx4.z+f[4*o4+2], hx4.w+f[4*o4+3]);
  }
}

// ---------------------------------------------------------------------------
// Final: layernorm -> pool score s; softmax over N per batch; weighted sum; fc
// ---------------------------------------------------------------------------
__global__ __launch_bounds__(256) void k_pool_score(
    const float* __restrict__ hbuf, const float* __restrict__ ng,
    const float* __restrict__ nb, const float* __restrict__ pw,
    const float* __restrict__ pb, float* __restrict__ s)
{
  const int tok = blockIdx.x*256 + threadIdx.x;
  float hx[32];
  const float4* src = (const float4*)(hbuf + (size_t)tok*32);
  #pragma unroll
  for (int i=0;i<8;i++){ float4 v4=src[i]; hx[4*i]=v4.x; hx[4*i+1]=v4.y; hx[4*i+2]=v4.z; hx[4*i+3]=v4.w; }
  float mu=0;
  #pragma unroll
  for (int i=0;i<32;i++) mu += hx[i];
  mu *= (1.0f/32.0f);
  float vs=0;
  #pragma unroll
  for (int i=0;i<32;i++){ float d=hx[i]-mu; vs += d*d; }
  const float inv = rsqrtf(vs*(1.0f/32.0f)+EPS);
  float sv = pb[0];
  #pragma unroll
  for (int i=0;i<32;i++) sv += ((hx[i]-mu)*inv*ng[i]+nb[i])*pw[i];
  s[tok]=sv;
}

__global__ __launch_bounds__(256) void k_softmax_stats(
    const float* __restrict__ s, float* __restrict__ bmax, float* __restrict__ bsum)
{
  __shared__ float red[256];
  __shared__ float smax_sh;
  const int b = blockIdx.x, tid = threadIdx.x;
  const float* sbp = s + (size_t)b*TOKB;
  float mx = -INFINITY;
  for (int i=tid;i<TOKB;i+=256) mx = fmaxf(mx, sbp[i]);
  red[tid]=mx; __syncthreads();
  for (int st=128;st>0;st>>=1){ if(tid<st) red[tid]=fmaxf(red[tid],red[tid+st]); __syncthreads(); }
  if (tid==0) smax_sh = red[0];
  __syncthreads();
  const float smax = smax_sh;
  float acc=0.0f;
  for (int i=tid;i<TOKB;i+=256) acc += __expf(sbp[i]-smax);
  __syncthreads();
  red[tid]=acc; __syncthreads();
  for (int st=128;st>0;st>>=1){ if(tid<st) red[tid]+=red[tid+st]; __syncthreads(); }
  if (tid==0){ bmax[b]=smax; bsum[b]=red[0]; }
}

__global__ __launch_bounds__(256) void k_pool_partial(
    const float* __restrict__ hbuf, const float* __restrict__ ng,
    const float* __restrict__ nb, const float* __restrict__ s,
    const float* __restrict__ bmax, float* __restrict__ pp)
{
  __shared__ float red[256][33];
  const int b = blockIdx.x/63, ch = blockIdx.x%63;
  const int tid = threadIdx.x;
  const int n = ch*256+tid;
  if (n < TOKB) {
    const int tok = b*TOKB+n;
    float hx[32];
    const float4* src = (const float4*)(hbuf + (size_t)tok*32);
    #pragma unroll
    for (int i=0;i<8;i++){ float4 v4=src[i]; hx[4*i]=v4.x; hx[4*i+1]=v4.y; hx[4*i+2]=v4.z; hx[4*i+3]=v4.w; }
    float mu=0;
    #pragma unroll
    for (int i=0;i<32;i++) mu += hx[i];
    mu *= (1.0f/32.0f);
    float vs=0;
    #pragma unroll
    for (int i=0;i<32;i++){ float d=hx[i]-mu; vs += d*d; }
    const float inv = rsqrtf(vs*(1.0f/32.0f)+EPS);
    const float w = __expf(s[tok]-bmax[b]);
    #pragma unroll
    for (int i=0;i<32;i++) red[tid][i] = w*((hx[i]-mu)*inv*ng[i]+nb[i]);
  } else {
    #pragma unroll
    for (int i=0;i<32;i++) red[tid][i]=0.0f;
  }
  __syncthreads();
  if (tid<32){
    float acc=0.0f;
    for (int t=0;t<256;t++) acc += red[t][tid];
    pp[(size_t)blockIdx.x*32 + tid] = acc;
  }
}

__global__ __launch_bounds__(64) void k_pool_final(
    const float* __restrict__ pp, const float* __restrict__ bsum,
    const float* __restrict__ fcw, const float* __restrict__ fcb,
    float* __restrict__ out)
{
  __shared__ float sp[32];
  const int b = blockIdx.x, tid = threadIdx.x;
  if (tid<32){
    float acc=0.0f;
    for (int ch=0;ch<63;ch++) acc += pp[(size_t)(b*63+ch)*32+tid];
    sp[tid] = acc / bsum[b];
  }
  __syncthreads();
  if (tid<2){
    float v = fcb[tid];
    for (int o=0;o<32;o++) v += sp[o]*fcw[o*2+tid];
    out[b*2+tid]=v;
  }
}

extern "C" void kernel_launch(void* const* d_in, const int* in_sizes, int n_in,
                              void* d_out, int out_size, void* d_ws, size_t ws_size,
                              hipStream_t stream)
{
  const float* x      = (const float*)d_in[0];
  const float* band_w = (const float*)d_in[1];
  const float* pw_w   = (const float*)d_in[2];
  const float* bn_g   = (const float*)d_in[3];
  const float* bn_b   = (const float*)d_in[4];
  const float* bn_m   = (const float*)d_in[5];
  const float* bn_v   = (const float*)d_in[6];
  const float* ln1_g  = (const float*)d_in[7];
  const float* ln1_b  = (const float*)d_in[8];
  const float* wqkv   = (const float*)d_in[9];
  const float* proj   = (const float*)d_in[10];
  const float* wproj  = (const float*)d_in[11];
  const float* bprojp = (const float*)d_in[12];
  const float* ln2_g  = (const float*)d_in[13];
  const float* ln2_b  = (const float*)d_in[14];
  const float* w1     = (const float*)d_in[15];
  const float* b1     = (const float*)d_in[16];
  const float* w2     = (const float*)d_in[17];
  const float* b2     = (const float*)d_in[18];
  const float* norm_g = (const float*)d_in[19];
  const float* norm_b = (const float*)d_in[20];
  const float* pool_w = (const float*)d_in[21];
  const float* pool_b = (const float*)d_in[22];
  const float* fc_w   = (const float*)d_in[23];
  const float* fc_b   = (const float*)d_in[24];
  float* out = (float*)d_out;
  float* ws  = (float*)d_ws;

  float* hbuf  = ws;                       // 8,192,000 floats (32 MB)
  float* kvp   = hbuf + 8192000;           // 2000*2048 = 4,096,000
  float* p2    = kvp  + 4096000;           // 10*2048 = 20,480
  float* KV    = p2   + 20480;             // 2048
  float* pmT   = KV   + 2048;              // 4096  (2 layers)
  float* w1T   = pmT  + 4096;              // 4096  (2 layers)
  float* sbuf  = w1T  + 4096;              // 256,000
  float* bmax  = sbuf + 256000;            // 16
  float* bsum  = bmax + 16;                // 16
  float* pp    = bsum + 16;                // 16*63*32 = 32,256

  k_prep<<<16,256,0,stream>>>(proj, w1, pmT, w1T);
  k_tokenize<<<1024,256,0,stream>>>(x, band_w, pw_w, bn_g, bn_b, bn_m, bn_v, hbuf);
  for (int l=0;l<2;l++){
    k_kv_partial<<<2000,256,0,stream>>>(hbuf, ln1_g+l*32, ln1_b+l*32,
                                        wqkv+l*3072, proj+l*2048, kvp);
    k_kv_reduce1<<<80,256,0,stream>>>(kvp, p2);
    k_kv_reduce2<<<1,256,0,stream>>>(p2, KV);
    k_attn<<<1000,256,0,stream>>>(hbuf, ln1_g+l*32, ln1_b+l*32,
                                  wqkv+l*3072, pmT+l*2048,
                                  wproj+l*1024, bprojp+l*32, KV);
    k_ffn<<<1000,256,0,stream>>>(hbuf, ln2_g+l*32, ln2_b+l*32,
                                 w1T+l*2048, b1+l*64, w2+l*2048, b2+l*32);
  }
  k_pool_score<<<1000,256,0,stream>>>(hbuf, norm_g, norm_b, pool_w, pool_b, sbuf);
  k_softmax_stats<<<16,256,0,stream>>>(sbuf, bmax, bsum);
  k_pool_partial<<<16*63,256,0,stream>>>(hbuf, norm_g, norm_b, sbuf, bmax, pp);
  k_pool_final<<<16,64,0,stream>>>(pp, bsum, fc_w, fc_b, out);
}

// Round 10
// 799.899 us; speedup vs baseline: 1.1014x; 1.1014x over previous
//
#include <hip/hip_runtime.h>
#include <math.h>

#define NTOK   256000
#define TOKB   16000
#define EPS    1e-5f

__device__ __forceinline__ float gelu_f(float x){
  return 0.5f*x*(1.0f+erff(x*0.70710678118654752440f));
}
__device__ __forceinline__ float elu1_f(float x){
  return x>0.0f ? x+1.0f : __expf(x);   // elu(x)+1
}

// ---------------------------------------------------------------------------
// Tokenizer: band conv(51) -> 1x1 conv(4->32) -> BN -> GELU -> avgpool(4)
// ---------------------------------------------------------------------------
__global__ __launch_bounds__(256) void k_tokenize(
    const float* __restrict__ x, const float* __restrict__ band_w,
    const float* __restrict__ pw_w, const float* __restrict__ bn_g,
    const float* __restrict__ bn_b, const float* __restrict__ bn_m,
    const float* __restrict__ bn_v, float* __restrict__ hout)
{
  __shared__ float sx[1050];
  __shared__ float sbw[4][51];
  __shared__ float spw[32][4];
  __shared__ float sscale[32], sshift[32];
  const int tid = threadIdx.x;
  const int b = blockIdx.x >> 6, e = blockIdx.x & 63;
  const float* xr = x + (size_t)(b*64 + e)*1000;
  for (int i=tid;i<1050;i+=256){ int t=i-25; sx[i]=(t>=0&&t<1000)?xr[t]:0.0f; }
  for (int i=tid;i<204;i+=256){ sbw[i/51][i%51] = band_w[i]; }
  for (int i=tid;i<128;i+=256){ spw[i>>2][i&3] = pw_w[i]; }
  if (tid<32){ float sc = bn_g[tid]*rsqrtf(bn_v[tid]+EPS);
               sscale[tid]=sc; sshift[tid]=bn_b[tid]-bn_m[tid]*sc; }
  __syncthreads();
  const int tp = tid;
  if (tp < 250) {
    float acc[32];
    #pragma unroll
    for (int o=0;o<32;o++) acc[o]=0.0f;
    for (int j=0;j<4;j++){
      const int t = 4*tp+j;
      float c0=0,c1=0,c2=0,c3=0;
      for (int k=0;k<51;k++){
        float xv = sx[t+k];
        c0 += xv*sbw[0][k]; c1 += xv*sbw[1][k];
        c2 += xv*sbw[2][k]; c3 += xv*sbw[3][k];
      }
      #pragma unroll
      for (int o=0;o<32;o++){
        float hv = spw[o][0]*c0 + spw[o][1]*c1 + spw[o][2]*c2 + spw[o][3]*c3;
        hv = hv*sscale[o] + sshift[o];
        acc[o] += gelu_f(hv);
      }
    }
    const int tok = b*TOKB + e*250 + tp;
    float4* dst = (float4*)(hout + (size_t)tok*32);
    #pragma unroll
    for (int o8=0;o8<8;o8++)
      dst[o8] = make_float4(acc[o8*4]*0.25f, acc[o8*4+1]*0.25f,
                            acc[o8*4+2]*0.25f, acc[o8*4+3]*0.25f);
  }
}

// ---------------------------------------------------------------------------
// Pass A: per 128-token tile: ln1 -> k,v -> K-features -> partial KV[h,f,d]
// (R7 proven version)
// ---------------------------------------------------------------------------
__global__ __launch_bounds__(256) void k_kv_partial(
    const float* __restrict__ hbuf, const float* __restrict__ ln1_g,
    const float* __restrict__ ln1_b, const float* __restrict__ wqkv,
    const float* __restrict__ proj_mat, float* __restrict__ kvpart, int l)
{
  __shared__ __align__(16) float sk[128][36];
  __shared__ __align__(16) float sv[128][36];
  __shared__ __align__(16) float swkT[64][32];
  __shared__ float sg[32], sb[32];
  const int tid = threadIdx.x;
  const float* W = wqkv + l*32*96;
  for (int idx=tid;idx<2048;idx+=256){
    int i = idx&31, j = idx>>5;
    swkT[j][i] = W[i*96 + 32 + j];
  }
  if (tid<32){ sg[tid]=ln1_g[l*32+tid]; sb[tid]=ln1_b[l*32+tid]; }
  __syncthreads();
  {
    const int tloc = tid>>1, half = tid&1;
    const int tok = blockIdx.x*128 + tloc;
    float hx[32];
    const float4* src = (const float4*)(hbuf + (size_t)tok*32);
    #pragma unroll
    for (int i=0;i<8;i++){ float4 v4=src[i]; hx[4*i]=v4.x; hx[4*i+1]=v4.y; hx[4*i+2]=v4.z; hx[4*i+3]=v4.w; }
    float mu=0;
    #pragma unroll
    for (int i=0;i<32;i++) mu += hx[i];
    mu *= (1.0f/32.0f);
    float vs=0;
    #pragma unroll
    for (int i=0;i<32;i++){ float d=hx[i]-mu; vs += d*d; }
    const float inv = rsqrtf(vs*(1.0f/32.0f)+EPS);
    float xn[32];
    #pragma unroll
    for (int i=0;i<32;i++) xn[i] = (hx[i]-mu)*inv*sg[i]+sb[i];
    const int j0 = half*16;
    #pragma unroll 4
    for (int jj=0;jj<16;jj++){
      const int j = j0+jj;
      const float4* wk4 = (const float4*)&swkT[j][0];
      const float4* wv4 = (const float4*)&swkT[32+j][0];
      float ka=0, va=0;
      #pragma unroll
      for (int i4=0;i4<8;i4++){
        float4 wk = wk4[i4], wv = wv4[i4];
        ka += xn[4*i4+0]*wk.x + xn[4*i4+1]*wk.y + xn[4*i4+2]*wk.z + xn[4*i4+3]*wk.w;
        va += xn[4*i4+0]*wv.x + xn[4*i4+1]*wv.y + xn[4*i4+2]*wv.z + xn[4*i4+3]*wv.w;
      }
      sk[tloc][j]=ka; sv[tloc][j]=va;
    }
  }
  __syncthreads();
  const int hh = tid>>6, f = tid&63;
  float pm0,pm1,pm2,pm3,pm4,pm5,pm6,pm7;
  {
    const float* pmp = proj_mat + ((size_t)(l*4+hh)*8)*64 + f;
    pm0=pmp[0]; pm1=pmp[64]; pm2=pmp[128]; pm3=pmp[192];
    pm4=pmp[256]; pm5=pmp[320]; pm6=pmp[384]; pm7=pmp[448];
  }
  float a0=0,a1=0,a2=0,a3=0,a4=0,a5=0,a6=0,a7=0;
  #pragma unroll 4
  for (int t=0;t<128;t++){
    const float4* k4 = (const float4*)&sk[t][hh*8];
    const float4* v4 = (const float4*)&sv[t][hh*8];
    float4 ka = k4[0], kb = k4[1];
    float kd = ka.x*pm0 + ka.y*pm1 + ka.z*pm2 + ka.w*pm3
             + kb.x*pm4 + kb.y*pm5 + kb.z*pm6 + kb.w*pm7;
    const float Kf = elu1_f(kd);
    float4 va = v4[0], vb = v4[1];
    a0 += Kf*va.x; a1 += Kf*va.y; a2 += Kf*va.z; a3 += Kf*va.w;
    a4 += Kf*vb.x; a5 += Kf*vb.y; a6 += Kf*vb.z; a7 += Kf*vb.w;
  }
  float4* dst = (float4*)(kvpart + (size_t)blockIdx.x*2048 + tid*8);
  dst[0] = make_float4(a0,a1,a2,a3);
  dst[1] = make_float4(a4,a5,a6,a7);
}

// fixed-order hierarchical KV reduction: 2000 partials -> 10 chunks -> final
__global__ __launch_bounds__(256) void k_kv_reduce1(
    const float* __restrict__ kvpart, float* __restrict__ p2)
{
  const int chunk = blockIdx.x >> 3;
  const int e = (blockIdx.x&7)*256 + threadIdx.x;
  float acc=0.0f;
  const int base = chunk*200;
  for (int ab=0; ab<200; ab++) acc += kvpart[(size_t)(base+ab)*2048 + e];
  p2[chunk*2048 + e] = acc;
}

__global__ __launch_bounds__(256) void k_kv_reduce2(
    const float* __restrict__ p2, float* __restrict__ KV)
{
  const int hf = threadIdx.x;
  float acc[8];
  #pragma unroll
  for (int d=0;d<8;d++) acc[d]=0.0f;
  for (int c=0;c<10;c++){
    #pragma unroll
    for (int d=0;d<8;d++) acc[d] += p2[c*2048 + hf*8 + d];
  }
  #pragma unroll
  for (int d=0;d<8;d++) KV[hf*8+d]=acc[d];
}

// ---------------------------------------------------------------------------
// Pass C1: thread handles TWO tokens (tok, tok+256). Every LDS weight read
// (wave-uniform broadcast) now serves 128 tokens/wave -> DS per token halves.
// All register arrays statically indexed.
// ---------------------------------------------------------------------------
__global__ __launch_bounds__(256) void k_attn(
    float* __restrict__ hbuf,
    const float* __restrict__ ln1_g, const float* __restrict__ ln1_b,
    const float* __restrict__ wqkv, const float* __restrict__ proj_mat,
    const float* __restrict__ wproj, const float* __restrict__ bproj,
    const float* __restrict__ KV, int l)
{
  __shared__ __align__(16) float swqT[32][32];   // [j][i]
  __shared__ __align__(16) float spmT[4][64][8]; // [h][f][d]
  __shared__ __align__(16) float sKVT[4][64][8]; // [h][f][d]
  __shared__ __align__(16) float swpT[32][32];   // [o][i]
  __shared__ float s1g[32], s1b[32], sbp[32];
  const int tid = threadIdx.x;
  for (int idx=tid; idx<1024; idx+=256){
    int j=idx>>5, i=idx&31;
    swqT[j][i] = wqkv[l*3072 + i*96 + j];
    swpT[j][i] = wproj[l*1024 + i*32 + j];
  }
  for (int i=tid;i<2048;i+=256){
    int hh=i>>9, f=(i>>3)&63, d=i&7;
    spmT[hh][f][d] = proj_mat[l*2048 + hh*512 + d*64 + f];
    (&sKVT[0][0][0])[i] = KV[i];
  }
  if (tid<32){ s1g[tid]=ln1_g[l*32+tid]; s1b[tid]=ln1_b[l*32+tid];
               sbp[tid]=bproj[l*32+tid]; }
  __syncthreads();

  const int tok0 = blockIdx.x*512 + tid;
  float4* hpA = (float4*)(hbuf + (size_t)tok0*32);
  float4* hpB = hpA + 256*8;          // token tok0+256

  // ---- ln1 for both tokens ----
  float xnA[32], xnB[32];
  {
    float hx[32];
    #pragma unroll
    for (int i=0;i<8;i++){ float4 v=hpA[i]; hx[4*i]=v.x; hx[4*i+1]=v.y; hx[4*i+2]=v.z; hx[4*i+3]=v.w; }
    float mu=0;
    #pragma unroll
    for (int i=0;i<32;i++) mu += hx[i];
    mu *= (1.0f/32.0f);
    float vs=0;
    #pragma unroll
    for (int i=0;i<32;i++){ float d=hx[i]-mu; vs += d*d; }
    const float inv = rsqrtf(vs*(1.0f/32.0f)+EPS);
    #pragma unroll
    for (int i=0;i<32;i++) xnA[i] = (hx[i]-mu)*inv*s1g[i]+s1b[i];
  }
  {
    float hx[32];
    #pragma unroll
    for (int i=0;i<8;i++){ float4 v=hpB[i]; hx[4*i]=v.x; hx[4*i+1]=v.y; hx[4*i+2]=v.z; hx[4*i+3]=v.w; }
    float mu=0;
    #pragma unroll
    for (int i=0;i<32;i++) mu += hx[i];
    mu *= (1.0f/32.0f);
    float vs=0;
    #pragma unroll
    for (int i=0;i<32;i++){ float d=hx[i]-mu; vs += d*d; }
    const float inv = rsqrtf(vs*(1.0f/32.0f)+EPS);
    #pragma unroll
    for (int i=0;i<32;i++) xnB[i] = (hx[i]-mu)*inv*s1g[i]+s1b[i];
  }

  // ---- q for both tokens (weight-row outer, tokens inner) ----
  float qA[32], qB[32];
  #pragma unroll
  for (int j=0;j<32;j++){
    const float4* wr = (const float4*)&swqT[j][0];
    float a=0, b=0;
    #pragma unroll
    for (int i4=0;i4<8;i4++){
      float4 w = wr[i4];
      a += xnA[4*i4+0]*w.x + xnA[4*i4+1]*w.y + xnA[4*i4+2]*w.z + xnA[4*i4+3]*w.w;
      b += xnB[4*i4+0]*w.x + xnB[4*i4+1]*w.y + xnB[4*i4+2]*w.z + xnB[4*i4+3]*w.w;
    }
    qA[j]=a; qB[j]=b;
  }

  // ---- attention per head; att overwrites q slices in place ----
  #pragma unroll
  for (int hh=0;hh<4;hh++){
    float aA0=0,aA1=0,aA2=0,aA3=0,aA4=0,aA5=0,aA6=0,aA7=0;
    float aB0=0,aB1=0,aB2=0,aB3=0,aB4=0,aB5=0,aB6=0,aB7=0;
    #pragma unroll 4
    for (int f=0;f<64;f++){
      const float4* pm4 = (const float4*)&spmT[hh][f][0];
      float4 pa = pm4[0], pb = pm4[1];
      float qdA = qA[hh*8+0]*pa.x+qA[hh*8+1]*pa.y+qA[hh*8+2]*pa.z+qA[hh*8+3]*pa.w
                + qA[hh*8+4]*pb.x+qA[hh*8+5]*pb.y+qA[hh*8+6]*pb.z+qA[hh*8+7]*pb.w;
      float qdB = qB[hh*8+0]*pa.x+qB[hh*8+1]*pa.y+qB[hh*8+2]*pa.z+qB[hh*8+3]*pa.w
                + qB[hh*8+4]*pb.x+qB[hh*8+5]*pb.y+qB[hh*8+6]*pb.z+qB[hh*8+7]*pb.w;
      const float QfA = elu1_f(qdA);
      const float QfB = elu1_f(qdB);
      const float4* kv4 = (const float4*)&sKVT[hh][f][0];
      float4 va = kv4[0], vb = kv4[1];
      aA0+=QfA*va.x; aA1+=QfA*va.y; aA2+=QfA*va.z; aA3+=QfA*va.w;
      aA4+=QfA*vb.x; aA5+=QfA*vb.y; aA6+=QfA*vb.z; aA7+=QfA*vb.w;
      aB0+=QfB*va.x; aB1+=QfB*va.y; aB2+=QfB*va.z; aB3+=QfB*va.w;
      aB4+=QfB*vb.x; aB5+=QfB*vb.y; aB6+=QfB*vb.z; aB7+=QfB*vb.w;
    }
    {
      const float z = 1.0f/(aA0+aA1+aA2+aA3+aA4+aA5+aA6+aA7);
      qA[hh*8+0]=aA0*z; qA[hh*8+1]=aA1*z; qA[hh*8+2]=aA2*z; qA[hh*8+3]=aA3*z;
      qA[hh*8+4]=aA4*z; qA[hh*8+5]=aA5*z; qA[hh*8+6]=aA6*z; qA[hh*8+7]=aA7*z;
    }
    {
      const float z = 1.0f/(aB0+aB1+aB2+aB3+aB4+aB5+aB6+aB7);
      qB[hh*8+0]=aB0*z; qB[hh*8+1]=aB1*z; qB[hh*8+2]=aB2*z; qB[hh*8+3]=aB3*z;
      qB[hh*8+4]=aB4*z; qB[hh*8+5]=aB5*z; qB[hh*8+6]=aB6*z; qB[hh*8+7]=aB7*z;
    }
  }

  // ---- proj + residual for both tokens ----
  #pragma unroll
  for (int o4=0;o4<8;o4++){
    float pA0=sbp[4*o4+0], pA1=sbp[4*o4+1], pA2=sbp[4*o4+2], pA3=sbp[4*o4+3];
    float pB0=pA0, pB1=pA1, pB2=pA2, pB3=pA3;
    const float4* w0 = (const float4*)&swpT[o4*4+0][0];
    const float4* w1r= (const float4*)&swpT[o4*4+1][0];
    const float4* w2r= (const float4*)&swpT[o4*4+2][0];
    const float4* w3 = (const float4*)&swpT[o4*4+3][0];
    #pragma unroll
    for (int i4=0;i4<8;i4++){
      float4 b0=w0[i4], b1=w1r[i4], b2=w2r[i4], b3=w3[i4];
      pA0 += qA[4*i4+0]*b0.x + qA[4*i4+1]*b0.y + qA[4*i4+2]*b0.z + qA[4*i4+3]*b0.w;
      pA1 += qA[4*i4+0]*b1.x + qA[4*i4+1]*b1.y + qA[4*i4+2]*b1.z + qA[4*i4+3]*b1.w;
      pA2 += qA[4*i4+0]*b2.x + qA[4*i4+1]*b2.y + qA[4*i4+2]*b2.z + qA[4*i4+3]*b2.w;
      pA3 += qA[4*i4+0]*b3.x + qA[4*i4+1]*b3.y + qA[4*i4+2]*b3.z + qA[4*i4+3]*b3.w;
      pB0 += qB[4*i4+0]*b0.x + qB[4*i4+1]*b0.y + qB[4*i4+2]*b0.z + qB[4*i4+3]*b0.w;
      pB1 += qB[4*i4+0]*b1.x + qB[4*i4+1]*b1.y + qB[4*i4+2]*b1.z + qB[4*i4+3]*b1.w;
      pB2 += qB[4*i4+0]*b2.x + qB[4*i4+1]*b2.y + qB[4*i4+2]*b2.z + qB[4*i4+3]*b2.w;
      pB3 += qB[4*i4+0]*b3.x + qB[4*i4+1]*b3.y + qB[4*i4+2]*b3.z + qB[4*i4+3]*b3.w;
    }
    float4 hA = hpA[o4];
    hpA[o4] = make_float4(hA.x+pA0, hA.y+pA1, hA.z+pA2, hA.w+pA3);
    float4 hB = hpB[o4];
    hpB[o4] = make_float4(hB.x+pB0, hB.y+pB1, hB.z+pB2, hB.w+pB3);
  }
}

// ---------------------------------------------------------------------------
// Pass C2: thread handles TWO tokens. ln2 -> FFN(gelu) -> residual.
// DS per j-iteration (16 b128) serves 128 tokens/wave.
// ---------------------------------------------------------------------------
__global__ __launch_bounds__(256) void k_ffn(
    float* __restrict__ hbuf,
    const float* __restrict__ ln2_g, const float* __restrict__ ln2_b,
    const float* __restrict__ w1, const float* __restrict__ b1,
    const float* __restrict__ w2, const float* __restrict__ b2, int l)
{
  __shared__ __align__(16) float w1T[64][32];   // [j][i]
  __shared__ __align__(16) float sw2[64][32];   // [j][c]
  __shared__ float s2g[32],s2b[32],sb1[64],sb2[32];
  const int tid = threadIdx.x;
  for (int idx=tid;idx<2048;idx+=256){
    int j=idx>>5, i=idx&31;
    w1T[j][i] = w1[l*2048 + i*64 + j];
    (&sw2[0][0])[idx] = w2[l*2048 + idx];
  }
  if (tid<32){ s2g[tid]=ln2_g[l*32+tid]; s2b[tid]=ln2_b[l*32+tid];
               sb2[tid]=b2[l*32+tid]; }
  if (tid<64) sb1[tid]=b1[l*64+tid];
  __syncthreads();

  const int tok0 = blockIdx.x*512 + tid;
  float4* hpA = (float4*)(hbuf + (size_t)tok0*32);
  float4* hpB = hpA + 256*8;

  // ---- ln2 for both tokens ----
  float mA[32], mB[32];
  {
    float hx[32];
    #pragma unroll
    for (int i=0;i<8;i++){ float4 v=hpA[i]; hx[4*i]=v.x; hx[4*i+1]=v.y; hx[4*i+2]=v.z; hx[4*i+3]=v.w; }
    float mu=0;
    #pragma unroll
    for (int i=0;i<32;i++) mu += hx[i];
    mu *= (1.0f/32.0f);
    float vs=0;
    #pragma unroll
    for (int i=0;i<32;i++){ float d=hx[i]-mu; vs += d*d; }
    const float inv = rsqrtf(vs*(1.0f/32.0f)+EPS);
    #pragma unroll
    for (int i=0;i<32;i++) mA[i] = (hx[i]-mu)*inv*s2g[i]+s2b[i];
  }
  {
    float hx[32];
    #pragma unroll
    for (int i=0;i<8;i++){ float4 v=hpB[i]; hx[4*i]=v.x; hx[4*i+1]=v.y; hx[4*i+2]=v.z; hx[4*i+3]=v.w; }
    float mu=0;
    #pragma unroll
    for (int i=0;i<32;i++) mu += hx[i];
    mu *= (1.0f/32.0f);
    float vs=0;
    #pragma unroll
    for (int i=0;i<32;i++){ float d=hx[i]-mu; vs += d*d; }
    const float inv = rsqrtf(vs*(1.0f/32.0f)+EPS);
    #pragma unroll
    for (int i=0;i<32;i++) mB[i] = (hx[i]-mu)*inv*s2g[i]+s2b[i];
  }

  float fA[32], fB[32];
  #pragma unroll
  for (int c=0;c<32;c++){ fA[c]=sb2[c]; fB[c]=sb2[c]; }

  #pragma unroll 2
  for (int j=0;j<64;j++){
    const float4* r1 = (const float4*)&w1T[j][0];
    float gA = sb1[j], gB = sb1[j];
    #pragma unroll
    for (int i4=0;i4<8;i4++){
      float4 w = r1[i4];
      gA += mA[4*i4+0]*w.x + mA[4*i4+1]*w.y + mA[4*i4+2]*w.z + mA[4*i4+3]*w.w;
      gB += mB[4*i4+0]*w.x + mB[4*i4+1]*w.y + mB[4*i4+2]*w.z + mB[4*i4+3]*w.w;
    }
    const float ggA = gelu_f(gA);
    const float ggB = gelu_f(gB);
    const float4* r2 = (const float4*)&sw2[j][0];
    #pragma unroll
    for (int c4=0;c4<8;c4++){
      float4 w = r2[c4];
      fA[4*c4+0] += ggA*w.x; fA[4*c4+1] += ggA*w.y; fA[4*c4+2] += ggA*w.z; fA[4*c4+3] += ggA*w.w;
      fB[4*c4+0] += ggB*w.x; fB[4*c4+1] += ggB*w.y; fB[4*c4+2] += ggB*w.z; fB[4*c4+3] += ggB*w.w;
    }
  }

  #pragma unroll
  for (int o4=0;o4<8;o4++){
    float4 hA = hpA[o4];
    hpA[o4] = make_float4(hA.x+fA[4*o4+0], hA.y+fA[4*o4+1],
                          hA.z+fA[4*o4+2], hA.w+fA[4*o4+3]);
    float4 hB = hpB[o4];
    hpB[o4] = make_float4(hB.x+fB[4*o4+0], hB.y+fB[4*o4+1],
                          hB.z+fB[4*o4+2], hB.w+fB[4*o4+3]);
  }
}

// ---------------------------------------------------------------------------
// Final: layernorm -> pool score s; softmax over N per batch; weighted sum; fc
// ---------------------------------------------------------------------------
__global__ __launch_bounds__(256) void k_pool_score(
    const float* __restrict__ hbuf, const float* __restrict__ ng,
    const float* __restrict__ nb, const float* __restrict__ pw,
    const float* __restrict__ pb, float* __restrict__ s)
{
  const int tok = blockIdx.x*256 + threadIdx.x;
  float hx[32];
  const float4* src = (const float4*)(hbuf + (size_t)tok*32);
  #pragma unroll
  for (int i=0;i<8;i++){ float4 v4=src[i]; hx[4*i]=v4.x; hx[4*i+1]=v4.y; hx[4*i+2]=v4.z; hx[4*i+3]=v4.w; }
  float mu=0;
  #pragma unroll
  for (int i=0;i<32;i++) mu += hx[i];
  mu *= (1.0f/32.0f);
  float vs=0;
  #pragma unroll
  for (int i=0;i<32;i++){ float d=hx[i]-mu; vs += d*d; }
  const float inv = rsqrtf(vs*(1.0f/32.0f)+EPS);
  float sv = pb[0];
  #pragma unroll
  for (int i=0;i<32;i++) sv += ((hx[i]-mu)*inv*ng[i]+nb[i])*pw[i];
  s[tok]=sv;
}

__global__ __launch_bounds__(256) void k_softmax_stats(
    const float* __restrict__ s, float* __restrict__ bmax, float* __restrict__ bsum)
{
  __shared__ float red[256];
  __shared__ float smax_sh;
  const int b = blockIdx.x, tid = threadIdx.x;
  const float* sbp = s + (size_t)b*TOKB;
  float mx = -INFINITY;
  for (int i=tid;i<TOKB;i+=256) mx = fmaxf(mx, sbp[i]);
  red[tid]=mx; __syncthreads();
  for (int st=128;st>0;st>>=1){ if(tid<st) red[tid]=fmaxf(red[tid],red[tid+st]); __syncthreads(); }
  if (tid==0) smax_sh = red[0];
  __syncthreads();
  const float smax = smax_sh;
  float acc=0.0f;
  for (int i=tid;i<TOKB;i+=256) acc += __expf(sbp[i]-smax);
  __syncthreads();
  red[tid]=acc; __syncthreads();
  for (int st=128;st>0;st>>=1){ if(tid<st) red[tid]+=red[tid+st]; __syncthreads(); }
  if (tid==0){ bmax[b]=smax; bsum[b]=red[0]; }
}

__global__ __launch_bounds__(256) void k_pool_partial(
    const float* __restrict__ hbuf, const float* __restrict__ ng,
    const float* __restrict__ nb, const float* __restrict__ s,
    const float* __restrict__ bmax, float* __restrict__ pp)
{
  __shared__ float red[256][33];
  const int b = blockIdx.x/63, ch = blockIdx.x%63;
  const int tid = threadIdx.x;
  const int n = ch*256+tid;
  if (n < TOKB) {
    const int tok = b*TOKB+n;
    float hx[32];
    const float4* src = (const float4*)(hbuf + (size_t)tok*32);
    #pragma unroll
    for (int i=0;i<8;i++){ float4 v4=src[i]; hx[4*i]=v4.x; hx[4*i+1]=v4.y; hx[4*i+2]=v4.z; hx[4*i+3]=v4.w; }
    float mu=0;
    #pragma unroll
    for (int i=0;i<32;i++) mu += hx[i];
    mu *= (1.0f/32.0f);
    float vs=0;
    #pragma unroll
    for (int i=0;i<32;i++){ float d=hx[i]-mu; vs += d*d; }
    const float inv = rsqrtf(vs*(1.0f/32.0f)+EPS);
    const float w = __expf(s[tok]-bmax[b]);
    #pragma unroll
    for (int i=0;i<32;i++) red[tid][i] = w*((hx[i]-mu)*inv*ng[i]+nb[i]);
  } else {
    #pragma unroll
    for (int i=0;i<32;i++) red[tid][i]=0.0f;
  }
  __syncthreads();
  if (tid<32){
    float acc=0.0f;
    for (int t=0;t<256;t++) acc += red[t][tid];
    pp[(size_t)blockIdx.x*32 + tid] = acc;
  }
}

__global__ __launch_bounds__(64) void k_pool_final(
    const float* __restrict__ pp, const float* __restrict__ bsum,
    const float* __restrict__ fcw, const float* __restrict__ fcb,
    float* __restrict__ out)
{
  __shared__ float sp[32];
  const int b = blockIdx.x, tid = threadIdx.x;
  if (tid<32){
    float acc=0.0f;
    for (int ch=0;ch<63;ch++) acc += pp[(size_t)(b*63+ch)*32+tid];
    sp[tid] = acc / bsum[b];
  }
  __syncthreads();
  if (tid<2){
    float v = fcb[tid];
    for (int o=0;o<32;o++) v += sp[o]*fcw[o*2+tid];
    out[b*2+tid]=v;
  }
}

extern "C" void kernel_launch(void* const* d_in, const int* in_sizes, int n_in,
                              void* d_out, int out_size, void* d_ws, size_t ws_size,
                              hipStream_t stream)
{
  const float* x      = (const float*)d_in[0];
  const float* band_w = (const float*)d_in[1];
  const float* pw_w   = (const float*)d_in[2];
  const float* bn_g   = (const float*)d_in[3];
  const float* bn_b   = (const float*)d_in[4];
  const float* bn_m   = (const float*)d_in[5];
  const float* bn_v   = (const float*)d_in[6];
  const float* ln1_g  = (const float*)d_in[7];
  const float* ln1_b  = (const float*)d_in[8];
  const float* wqkv   = (const float*)d_in[9];
  const float* proj   = (const float*)d_in[10];
  const float* wproj  = (const float*)d_in[11];
  const float* bprojp = (const float*)d_in[12];
  const float* ln2_g  = (const float*)d_in[13];
  const float* ln2_b  = (const float*)d_in[14];
  const float* w1     = (const float*)d_in[15];
  const float* b1     = (const float*)d_in[16];
  const float* w2     = (const float*)d_in[17];
  const float* b2     = (const float*)d_in[18];
  const float* norm_g = (const float*)d_in[19];
  const float* norm_b = (const float*)d_in[20];
  const float* pool_w = (const float*)d_in[21];
  const float* pool_b = (const float*)d_in[22];
  const float* fc_w   = (const float*)d_in[23];
  const float* fc_b   = (const float*)d_in[24];
  float* out = (float*)d_out;
  float* ws  = (float*)d_ws;

  float* hbuf  = ws;                       // 8,192,000 floats (32 MB)
  float* kvp   = hbuf + 8192000;           // 2000*2048 = 4,096,000
  float* p2    = kvp  + 4096000;           // 10*2048 = 20,480
  float* KV    = p2   + 20480;             // 2048
  float* sbuf  = KV   + 2048;              // 256,000
  float* bmax  = sbuf + 256000;            // 16
  float* bsum  = bmax + 16;                // 16
  float* pp    = bsum + 16;                // 16*63*32 = 32,256

  k_tokenize<<<1024,256,0,stream>>>(x, band_w, pw_w, bn_g, bn_b, bn_m, bn_v, hbuf);
  for (int l=0;l<2;l++){
    k_kv_partial<<<2000,256,0,stream>>>(hbuf, ln1_g, ln1_b, wqkv, proj, kvp, l);
    k_kv_reduce1<<<80,256,0,stream>>>(kvp, p2);
    k_kv_reduce2<<<1,256,0,stream>>>(p2, KV);
    k_attn<<<500,256,0,stream>>>(hbuf, ln1_g, ln1_b, wqkv, proj, wproj, bprojp, KV, l);
    k_ffn<<<500,256,0,stream>>>(hbuf, ln2_g, ln2_b, w1, b1, w2, b2, l);
  }
  k_pool_score<<<1000,256,0,stream>>>(hbuf, norm_g, norm_b, pool_w, pool_b, sbuf);
  k_softmax_stats<<<16,256,0,stream>>>(sbuf, bmax, bsum);
  k_pool_partial<<<16*63,256,0,stream>>>(hbuf, norm_g, norm_b, sbuf, bmax, pp);
  k_pool_final<<<16,64,0,stream>>>(pp, bsum, fc_w, fc_b, out);
}

// Round 12
// 664.507 us; speedup vs baseline: 1.3258x; 1.2037x over previous
//
#include <hip/hip_runtime.h>
#include <math.h>

#define NTOK   256000
#define TOKB   16000
#define EPS    1e-5f

__device__ __forceinline__ float gelu_f(float x){
  return 0.5f*x*(1.0f+erff(x*0.70710678118654752440f));
}
__device__ __forceinline__ float elu1_f(float x){
  return x>0.0f ? x+1.0f : __expf(x);   // elu(x)+1
}

// ---------------------------------------------------------------------------
// Tokenizer: band conv(51) -> 1x1 conv(4->32) -> BN -> GELU -> avgpool(4)
// ---------------------------------------------------------------------------
__global__ __launch_bounds__(256) void k_tokenize(
    const float* __restrict__ x, const float* __restrict__ band_w,
    const float* __restrict__ pw_w, const float* __restrict__ bn_g,
    const float* __restrict__ bn_b, const float* __restrict__ bn_m,
    const float* __restrict__ bn_v, float* __restrict__ hout)
{
  __shared__ float sx[1050];
  __shared__ float sbw[4][51];
  __shared__ float spw[32][4];
  __shared__ float sscale[32], sshift[32];
  const int tid = threadIdx.x;
  const int b = blockIdx.x >> 6, e = blockIdx.x & 63;
  const float* xr = x + (size_t)(b*64 + e)*1000;
  for (int i=tid;i<1050;i+=256){ int t=i-25; sx[i]=(t>=0&&t<1000)?xr[t]:0.0f; }
  for (int i=tid;i<204;i+=256){ sbw[i/51][i%51] = band_w[i]; }
  for (int i=tid;i<128;i+=256){ spw[i>>2][i&3] = pw_w[i]; }
  if (tid<32){ float sc = bn_g[tid]*rsqrtf(bn_v[tid]+EPS);
               sscale[tid]=sc; sshift[tid]=bn_b[tid]-bn_m[tid]*sc; }
  __syncthreads();
  const int tp = tid;
  if (tp < 250) {
    float acc[32];
    #pragma unroll
    for (int o=0;o<32;o++) acc[o]=0.0f;
    for (int j=0;j<4;j++){
      const int t = 4*tp+j;
      float c0=0,c1=0,c2=0,c3=0;
      for (int k=0;k<51;k++){
        float xv = sx[t+k];
        c0 += xv*sbw[0][k]; c1 += xv*sbw[1][k];
        c2 += xv*sbw[2][k]; c3 += xv*sbw[3][k];
      }
      #pragma unroll
      for (int o=0;o<32;o++){
        float hv = spw[o][0]*c0 + spw[o][1]*c1 + spw[o][2]*c2 + spw[o][3]*c3;
        hv = hv*sscale[o] + sshift[o];
        acc[o] += gelu_f(hv);
      }
    }
    const int tok = b*TOKB + e*250 + tp;
    float4* dst = (float4*)(hout + (size_t)tok*32);
    #pragma unroll
    for (int o8=0;o8<8;o8++)
      dst[o8] = make_float4(acc[o8*4]*0.25f, acc[o8*4+1]*0.25f,
                            acc[o8*4+2]*0.25f, acc[o8*4+3]*0.25f);
  }
}

// ---------------------------------------------------------------------------
// Pass A: per 128-token tile: ln1 -> k,v -> K-features -> partial KV[h,f,d]
// (R7 proven version)
// ---------------------------------------------------------------------------
__global__ __launch_bounds__(256) void k_kv_partial(
    const float* __restrict__ hbuf, const float* __restrict__ ln1_g,
    const float* __restrict__ ln1_b, const float* __restrict__ wqkv,
    const float* __restrict__ proj_mat, float* __restrict__ kvpart, int l)
{
  __shared__ __align__(16) float sk[128][36];
  __shared__ __align__(16) float sv[128][36];
  __shared__ __align__(16) float swkT[64][32];
  __shared__ float sg[32], sb[32];
  const int tid = threadIdx.x;
  const float* W = wqkv + l*32*96;
  for (int idx=tid;idx<2048;idx+=256){
    int i = idx&31, j = idx>>5;
    swkT[j][i] = W[i*96 + 32 + j];
  }
  if (tid<32){ sg[tid]=ln1_g[l*32+tid]; sb[tid]=ln1_b[l*32+tid]; }
  __syncthreads();
  {
    const int tloc = tid>>1, half = tid&1;
    const int tok = blockIdx.x*128 + tloc;
    float hx[32];
    const float4* src = (const float4*)(hbuf + (size_t)tok*32);
    #pragma unroll
    for (int i=0;i<8;i++){ float4 v4=src[i]; hx[4*i]=v4.x; hx[4*i+1]=v4.y; hx[4*i+2]=v4.z; hx[4*i+3]=v4.w; }
    float mu=0;
    #pragma unroll
    for (int i=0;i<32;i++) mu += hx[i];
    mu *= (1.0f/32.0f);
    float vs=0;
    #pragma unroll
    for (int i=0;i<32;i++){ float d=hx[i]-mu; vs += d*d; }
    const float inv = rsqrtf(vs*(1.0f/32.0f)+EPS);
    float xn[32];
    #pragma unroll
    for (int i=0;i<32;i++) xn[i] = (hx[i]-mu)*inv*sg[i]+sb[i];
    const int j0 = half*16;
    #pragma unroll 4
    for (int jj=0;jj<16;jj++){
      const int j = j0+jj;
      const float4* wk4 = (const float4*)&swkT[j][0];
      const float4* wv4 = (const float4*)&swkT[32+j][0];
      float ka=0, va=0;
      #pragma unroll
      for (int i4=0;i4<8;i4++){
        float4 wk = wk4[i4], wv = wv4[i4];
        ka += xn[4*i4+0]*wk.x + xn[4*i4+1]*wk.y + xn[4*i4+2]*wk.z + xn[4*i4+3]*wk.w;
        va += xn[4*i4+0]*wv.x + xn[4*i4+1]*wv.y + xn[4*i4+2]*wv.z + xn[4*i4+3]*wv.w;
      }
      sk[tloc][j]=ka; sv[tloc][j]=va;
    }
  }
  __syncthreads();
  const int hh = tid>>6, f = tid&63;
  float pm0,pm1,pm2,pm3,pm4,pm5,pm6,pm7;
  {
    const float* pmp = proj_mat + ((size_t)(l*4+hh)*8)*64 + f;
    pm0=pmp[0]; pm1=pmp[64]; pm2=pmp[128]; pm3=pmp[192];
    pm4=pmp[256]; pm5=pmp[320]; pm6=pmp[384]; pm7=pmp[448];
  }
  float a0=0,a1=0,a2=0,a3=0,a4=0,a5=0,a6=0,a7=0;
  #pragma unroll 4
  for (int t=0;t<128;t++){
    const float4* k4 = (const float4*)&sk[t][hh*8];
    const float4* v4 = (const float4*)&sv[t][hh*8];
    float4 ka = k4[0], kb = k4[1];
    float kd = ka.x*pm0 + ka.y*pm1 + ka.z*pm2 + ka.w*pm3
             + kb.x*pm4 + kb.y*pm5 + kb.z*pm6 + kb.w*pm7;
    const float Kf = elu1_f(kd);
    float4 va = v4[0], vb = v4[1];
    a0 += Kf*va.x; a1 += Kf*va.y; a2 += Kf*va.z; a3 += Kf*va.w;
    a4 += Kf*vb.x; a5 += Kf*vb.y; a6 += Kf*vb.z; a7 += Kf*vb.w;
  }
  float4* dst = (float4*)(kvpart + (size_t)blockIdx.x*2048 + tid*8);
  dst[0] = make_float4(a0,a1,a2,a3);
  dst[1] = make_float4(a4,a5,a6,a7);
}

// fixed-order hierarchical KV reduction: 2000 partials -> 10 chunks -> final
__global__ __launch_bounds__(256) void k_kv_reduce1(
    const float* __restrict__ kvpart, float* __restrict__ p2)
{
  const int chunk = blockIdx.x >> 3;
  const int e = (blockIdx.x&7)*256 + threadIdx.x;
  float acc=0.0f;
  const int base = chunk*200;
  for (int ab=0; ab<200; ab++) acc += kvpart[(size_t)(base+ab)*2048 + e];
  p2[chunk*2048 + e] = acc;
}

__global__ __launch_bounds__(256) void k_kv_reduce2(
    const float* __restrict__ p2, float* __restrict__ KV)
{
  const int hf = threadIdx.x;
  float acc[8];
  #pragma unroll
  for (int d=0;d<8;d++) acc[d]=0.0f;
  for (int c=0;c<10;c++){
    #pragma unroll
    for (int d=0;d<8;d++) acc[d] += p2[c*2048 + hf*8 + d];
  }
  #pragma unroll
  for (int d=0;d<8;d++) KV[hf*8+d]=acc[d];
}

// ---------------------------------------------------------------------------
// Pass C1: TWO tokens/thread, register-phased to avoid R10's spill:
// ln1+q computed token-sequentially in closed scopes (peak live ~96 regs);
// only the dominant f-loop and proj are token-inner (qA,qB = 64 regs + acc).
// ---------------------------------------------------------------------------
__global__ __launch_bounds__(256) void k_attn(
    float* __restrict__ hbuf,
    const float* __restrict__ ln1_g, const float* __restrict__ ln1_b,
    const float* __restrict__ wqkv, const float* __restrict__ proj_mat,
    const float* __restrict__ wproj, const float* __restrict__ bproj,
    const float* __restrict__ KV, int l)
{
  __shared__ __align__(16) float swqT[32][32];   // [j][i]
  __shared__ __align__(16) float spmT[4][64][8]; // [h][f][d]
  __shared__ __align__(16) float sKVT[4][64][8]; // [h][f][d]
  __shared__ __align__(16) float swpT[32][32];   // [o][i]
  __shared__ float s1g[32], s1b[32], sbp[32];
  const int tid = threadIdx.x;
  for (int idx=tid; idx<1024; idx+=256){
    int j=idx>>5, i=idx&31;
    swqT[j][i] = wqkv[l*3072 + i*96 + j];
    swpT[j][i] = wproj[l*1024 + i*32 + j];
  }
  for (int i=tid;i<2048;i+=256){
    int hh=i>>9, f=(i>>3)&63, d=i&7;
    spmT[hh][f][d] = proj_mat[l*2048 + hh*512 + d*64 + f];
    (&sKVT[0][0][0])[i] = KV[i];
  }
  if (tid<32){ s1g[tid]=ln1_g[l*32+tid]; s1b[tid]=ln1_b[l*32+tid];
               sbp[tid]=bproj[l*32+tid]; }
  __syncthreads();

  const int tok0 = blockIdx.x*512 + tid;
  float4* hpA = (float4*)(hbuf + (size_t)tok0*32);
  float4* hpB = hpA + 256*8;          // token tok0+256

  // ---- token A: ln1 -> q (closed scope; xn dies here) ----
  float qA[32];
  {
    float xn[32];
    {
      float hx[32];
      #pragma unroll
      for (int i=0;i<8;i++){ float4 v=hpA[i]; hx[4*i]=v.x; hx[4*i+1]=v.y; hx[4*i+2]=v.z; hx[4*i+3]=v.w; }
      float mu=0;
      #pragma unroll
      for (int i=0;i<32;i++) mu += hx[i];
      mu *= (1.0f/32.0f);
      float vs=0;
      #pragma unroll
      for (int i=0;i<32;i++){ float d=hx[i]-mu; vs += d*d; }
      const float inv = rsqrtf(vs*(1.0f/32.0f)+EPS);
      #pragma unroll
      for (int i=0;i<32;i++) xn[i] = (hx[i]-mu)*inv*s1g[i]+s1b[i];
    }
    #pragma unroll 4
    for (int j=0;j<32;j++){
      const float4* wr = (const float4*)&swqT[j][0];
      float a=0;
      #pragma unroll
      for (int i4=0;i4<8;i4++){
        float4 w = wr[i4];
        a += xn[4*i4+0]*w.x + xn[4*i4+1]*w.y + xn[4*i4+2]*w.z + xn[4*i4+3]*w.w;
      }
      qA[j]=a;
    }
  }
  // ---- token B: ln1 -> q ----
  float qB[32];
  {
    float xn[32];
    {
      float hx[32];
      #pragma unroll
      for (int i=0;i<8;i++){ float4 v=hpB[i]; hx[4*i]=v.x; hx[4*i+1]=v.y; hx[4*i+2]=v.z; hx[4*i+3]=v.w; }
      float mu=0;
      #pragma unroll
      for (int i=0;i<32;i++) mu += hx[i];
      mu *= (1.0f/32.0f);
      float vs=0;
      #pragma unroll
      for (int i=0;i<32;i++){ float d=hx[i]-mu; vs += d*d; }
      const float inv = rsqrtf(vs*(1.0f/32.0f)+EPS);
      #pragma unroll
      for (int i=0;i<32;i++) xn[i] = (hx[i]-mu)*inv*s1g[i]+s1b[i];
    }
    #pragma unroll 4
    for (int j=0;j<32;j++){
      const float4* wr = (const float4*)&swqT[j][0];
      float a=0;
      #pragma unroll
      for (int i4=0;i4<8;i4++){
        float4 w = wr[i4];
        a += xn[4*i4+0]*w.x + xn[4*i4+1]*w.y + xn[4*i4+2]*w.z + xn[4*i4+3]*w.w;
      }
      qB[j]=a;
    }
  }

  // ---- attention per head; token-inner f-loop (weights serve both) ----
  #pragma unroll
  for (int hh=0;hh<4;hh++){
    float aA0=0,aA1=0,aA2=0,aA3=0,aA4=0,aA5=0,aA6=0,aA7=0;
    float aB0=0,aB1=0,aB2=0,aB3=0,aB4=0,aB5=0,aB6=0,aB7=0;
    #pragma unroll 2
    for (int f=0;f<64;f++){
      const float4* pm4 = (const float4*)&spmT[hh][f][0];
      float4 pa = pm4[0], pb = pm4[1];
      float qdA = qA[hh*8+0]*pa.x+qA[hh*8+1]*pa.y+qA[hh*8+2]*pa.z+qA[hh*8+3]*pa.w
                + qA[hh*8+4]*pb.x+qA[hh*8+5]*pb.y+qA[hh*8+6]*pb.z+qA[hh*8+7]*pb.w;
      float qdB = qB[hh*8+0]*pa.x+qB[hh*8+1]*pa.y+qB[hh*8+2]*pa.z+qB[hh*8+3]*pa.w
                + qB[hh*8+4]*pb.x+qB[hh*8+5]*pb.y+qB[hh*8+6]*pb.z+qB[hh*8+7]*pb.w;
      const float QfA = elu1_f(qdA);
      const float QfB = elu1_f(qdB);
      const float4* kv4 = (const float4*)&sKVT[hh][f][0];
      float4 va = kv4[0], vb = kv4[1];
      aA0+=QfA*va.x; aA1+=QfA*va.y; aA2+=QfA*va.z; aA3+=QfA*va.w;
      aA4+=QfA*vb.x; aA5+=QfA*vb.y; aA6+=QfA*vb.z; aA7+=QfA*vb.w;
      aB0+=QfB*va.x; aB1+=QfB*va.y; aB2+=QfB*va.z; aB3+=QfB*va.w;
      aB4+=QfB*vb.x; aB5+=QfB*vb.y; aB6+=QfB*vb.z; aB7+=QfB*vb.w;
    }
    {
      const float z = 1.0f/(aA0+aA1+aA2+aA3+aA4+aA5+aA6+aA7);
      qA[hh*8+0]=aA0*z; qA[hh*8+1]=aA1*z; qA[hh*8+2]=aA2*z; qA[hh*8+3]=aA3*z;
      qA[hh*8+4]=aA4*z; qA[hh*8+5]=aA5*z; qA[hh*8+6]=aA6*z; qA[hh*8+7]=aA7*z;
    }
    {
      const float z = 1.0f/(aB0+aB1+aB2+aB3+aB4+aB5+aB6+aB7);
      qB[hh*8+0]=aB0*z; qB[hh*8+1]=aB1*z; qB[hh*8+2]=aB2*z; qB[hh*8+3]=aB3*z;
      qB[hh*8+4]=aB4*z; qB[hh*8+5]=aB5*z; qB[hh*8+6]=aB6*z; qB[hh*8+7]=aB7*z;
    }
  }

  // ---- proj + residual for both tokens (token-inner) ----
  #pragma unroll 2
  for (int o4=0;o4<8;o4++){
    float pA0=sbp[4*o4+0], pA1=sbp[4*o4+1], pA2=sbp[4*o4+2], pA3=sbp[4*o4+3];
    float pB0=pA0, pB1=pA1, pB2=pA2, pB3=pA3;
    const float4* w0 = (const float4*)&swpT[o4*4+0][0];
    const float4* w1r= (const float4*)&swpT[o4*4+1][0];
    const float4* w2r= (const float4*)&swpT[o4*4+2][0];
    const float4* w3 = (const float4*)&swpT[o4*4+3][0];
    #pragma unroll
    for (int i4=0;i4<8;i4++){
      float4 b0=w0[i4], b1=w1r[i4], b2=w2r[i4], b3=w3[i4];
      pA0 += qA[4*i4+0]*b0.x + qA[4*i4+1]*b0.y + qA[4*i4+2]*b0.z + qA[4*i4+3]*b0.w;
      pA1 += qA[4*i4+0]*b1.x + qA[4*i4+1]*b1.y + qA[4*i4+2]*b1.z + qA[4*i4+3]*b1.w;
      pA2 += qA[4*i4+0]*b2.x + qA[4*i4+1]*b2.y + qA[4*i4+2]*b2.z + qA[4*i4+3]*b2.w;
      pA3 += qA[4*i4+0]*b3.x + qA[4*i4+1]*b3.y + qA[4*i4+2]*b3.z + qA[4*i4+3]*b3.w;
      pB0 += qB[4*i4+0]*b0.x + qB[4*i4+1]*b0.y + qB[4*i4+2]*b0.z + qB[4*i4+3]*b0.w;
      pB1 += qB[4*i4+0]*b1.x + qB[4*i4+1]*b1.y + qB[4*i4+2]*b1.z + qB[4*i4+3]*b1.w;
      pB2 += qB[4*i4+0]*b2.x + qB[4*i4+1]*b2.y + qB[4*i4+2]*b2.z + qB[4*i4+3]*b2.w;
      pB3 += qB[4*i4+0]*b3.x + qB[4*i4+1]*b3.y + qB[4*i4+2]*b3.z + qB[4*i4+3]*b3.w;
    }
    float4 hA = hpA[o4];
    hpA[o4] = make_float4(hA.x+pA0, hA.y+pA1, hA.z+pA2, hA.w+pA3);
    float4 hB = hpB[o4];
    hpB[o4] = make_float4(hB.x+pB0, hB.y+pB1, hB.z+pB2, hB.w+pB3);
  }
}

// ---------------------------------------------------------------------------
// Pass C2: thread handles TWO tokens (R10, worked). ln2 -> FFN -> residual.
// ---------------------------------------------------------------------------
__global__ __launch_bounds__(256) void k_ffn(
    float* __restrict__ hbuf,
    const float* __restrict__ ln2_g, const float* __restrict__ ln2_b,
    const float* __restrict__ w1, const float* __restrict__ b1,
    const float* __restrict__ w2, const float* __restrict__ b2, int l)
{
  __shared__ __align__(16) float w1T[64][32];   // [j][i]
  __shared__ __align__(16) float sw2[64][32];   // [j][c]
  __shared__ float s2g[32],s2b[32],sb1[64],sb2[32];
  const int tid = threadIdx.x;
  for (int idx=tid;idx<2048;idx+=256){
    int j=idx>>5, i=idx&31;
    w1T[j][i] = w1[l*2048 + i*64 + j];
    (&sw2[0][0])[idx] = w2[l*2048 + idx];
  }
  if (tid<32){ s2g[tid]=ln2_g[l*32+tid]; s2b[tid]=ln2_b[l*32+tid];
               sb2[tid]=b2[l*32+tid]; }
  if (tid<64) sb1[tid]=b1[l*64+tid];
  __syncthreads();

  const int tok0 = blockIdx.x*512 + tid;
  float4* hpA = (float4*)(hbuf + (size_t)tok0*32);
  float4* hpB = hpA + 256*8;

  float mA[32], mB[32];
  {
    float hx[32];
    #pragma unroll
    for (int i=0;i<8;i++){ float4 v=hpA[i]; hx[4*i]=v.x; hx[4*i+1]=v.y; hx[4*i+2]=v.z; hx[4*i+3]=v.w; }
    float mu=0;
    #pragma unroll
    for (int i=0;i<32;i++) mu += hx[i];
    mu *= (1.0f/32.0f);
    float vs=0;
    #pragma unroll
    for (int i=0;i<32;i++){ float d=hx[i]-mu; vs += d*d; }
    const float inv = rsqrtf(vs*(1.0f/32.0f)+EPS);
    #pragma unroll
    for (int i=0;i<32;i++) mA[i] = (hx[i]-mu)*inv*s2g[i]+s2b[i];
  }
  {
    float hx[32];
    #pragma unroll
    for (int i=0;i<8;i++){ float4 v=hpB[i]; hx[4*i]=v.x; hx[4*i+1]=v.y; hx[4*i+2]=v.z; hx[4*i+3]=v.w; }
    float mu=0;
    #pragma unroll
    for (int i=0;i<32;i++) mu += hx[i];
    mu *= (1.0f/32.0f);
    float vs=0;
    #pragma unroll
    for (int i=0;i<32;i++){ float d=hx[i]-mu; vs += d*d; }
    const float inv = rsqrtf(vs*(1.0f/32.0f)+EPS);
    #pragma unroll
    for (int i=0;i<32;i++) mB[i] = (hx[i]-mu)*inv*s2g[i]+s2b[i];
  }

  float fA[32], fB[32];
  #pragma unroll
  for (int c=0;c<32;c++){ fA[c]=sb2[c]; fB[c]=sb2[c]; }

  #pragma unroll 2
  for (int j=0;j<64;j++){
    const float4* r1 = (const float4*)&w1T[j][0];
    float gA = sb1[j], gB = sb1[j];
    #pragma unroll
    for (int i4=0;i4<8;i4++){
      float4 w = r1[i4];
      gA += mA[4*i4+0]*w.x + mA[4*i4+1]*w.y + mA[4*i4+2]*w.z + mA[4*i4+3]*w.w;
      gB += mB[4*i4+0]*w.x + mB[4*i4+1]*w.y + mB[4*i4+2]*w.z + mB[4*i4+3]*w.w;
    }
    const float ggA = gelu_f(gA);
    const float ggB = gelu_f(gB);
    const float4* r2 = (const float4*)&sw2[j][0];
    #pragma unroll
    for (int c4=0;c4<8;c4++){
      float4 w = r2[c4];
      fA[4*c4+0] += ggA*w.x; fA[4*c4+1] += ggA*w.y; fA[4*c4+2] += ggA*w.z; fA[4*c4+3] += ggA*w.w;
      fB[4*c4+0] += ggB*w.x; fB[4*c4+1] += ggB*w.y; fB[4*c4+2] += ggB*w.z; fB[4*c4+3] += ggB*w.w;
    }
  }

  #pragma unroll
  for (int o4=0;o4<8;o4++){
    float4 hA = hpA[o4];
    hpA[o4] = make_float4(hA.x+fA[4*o4+0], hA.y+fA[4*o4+1],
                          hA.z+fA[4*o4+2], hA.w+fA[4*o4+3]);
    float4 hB = hpB[o4];
    hpB[o4] = make_float4(hB.x+fB[4*o4+0], hB.y+fB[4*o4+1],
                          hB.z+fB[4*o4+2], hB.w+fB[4*o4+3]);
  }
}

// ---------------------------------------------------------------------------
// Final: layernorm -> pool score s; softmax over N per batch; weighted sum; fc
// ---------------------------------------------------------------------------
__global__ __launch_bounds__(256) void k_pool_score(
    const float* __restrict__ hbuf, const float* __restrict__ ng,
    const float* __restrict__ nb, const float* __restrict__ pw,
    const float* __restrict__ pb, float* __restrict__ s)
{
  const int tok = blockIdx.x*256 + threadIdx.x;
  float hx[32];
  const float4* src = (const float4*)(hbuf + (size_t)tok*32);
  #pragma unroll
  for (int i=0;i<8;i++){ float4 v4=src[i]; hx[4*i]=v4.x; hx[4*i+1]=v4.y; hx[4*i+2]=v4.z; hx[4*i+3]=v4.w; }
  float mu=0;
  #pragma unroll
  for (int i=0;i<32;i++) mu += hx[i];
  mu *= (1.0f/32.0f);
  float vs=0;
  #pragma unroll
  for (int i=0;i<32;i++){ float d=hx[i]-mu; vs += d*d; }
  const float inv = rsqrtf(vs*(1.0f/32.0f)+EPS);
  float sv = pb[0];
  #pragma unroll
  for (int i=0;i<32;i++) sv += ((hx[i]-mu)*inv*ng[i]+nb[i])*pw[i];
  s[tok]=sv;
}

__global__ __launch_bounds__(256) void k_softmax_stats(
    const float* __restrict__ s, float* __restrict__ bmax, float* __restrict__ bsum)
{
  __shared__ float red[256];
  __shared__ float smax_sh;
  const int b = blockIdx.x, tid = threadIdx.x;
  const float* sbp = s + (size_t)b*TOKB;
  float mx = -INFINITY;
  for (int i=tid;i<TOKB;i+=256) mx = fmaxf(mx, sbp[i]);
  red[tid]=mx; __syncthreads();
  for (int st=128;st>0;st>>=1){ if(tid<st) red[tid]=fmaxf(red[tid],red[tid+st]); __syncthreads(); }
  if (tid==0) smax_sh = red[0];
  __syncthreads();
  const float smax = smax_sh;
  float acc=0.0f;
  for (int i=tid;i<TOKB;i+=256) acc += __expf(sbp[i]-smax);
  __syncthreads();
  red[tid]=acc; __syncthreads();
  for (int st=128;st>0;st>>=1){ if(tid<st) red[tid]+=red[tid+st]; __syncthreads(); }
  if (tid==0){ bmax[b]=smax; bsum[b]=red[0]; }
}

__global__ __launch_bounds__(256) void k_pool_partial(
    const float* __restrict__ hbuf, const float* __restrict__ ng,
    const float* __restrict__ nb, const float* __restrict__ s,
    const float* __restrict__ bmax, float* __restrict__ pp)
{
  __shared__ float red[256][33];
  const int b = blockIdx.x/63, ch = blockIdx.x%63;
  const int tid = threadIdx.x;
  const int n = ch*256+tid;
  if (n < TOKB) {
    const int tok = b*TOKB+n;
    float hx[32];
    const float4* src = (const float4*)(hbuf + (size_t)tok*32);
    #pragma unroll
    for (int i=0;i<8;i++){ float4 v4=src[i]; hx[4*i]=v4.x; hx[4*i+1]=v4.y; hx[4*i+2]=v4.z; hx[4*i+3]=v4.w; }
    float mu=0;
    #pragma unroll
    for (int i=0;i<32;i++) mu += hx[i];
    mu *= (1.0f/32.0f);
    float vs=0;
    #pragma unroll
    for (int i=0;i<32;i++){ float d=hx[i]-mu; vs += d*d; }
    const float inv = rsqrtf(vs*(1.0f/32.0f)+EPS);
    const float w = __expf(s[tok]-bmax[b]);
    #pragma unroll
    for (int i=0;i<32;i++) red[tid][i] = w*((hx[i]-mu)*inv*ng[i]+nb[i]);
  } else {
    #pragma unroll
    for (int i=0;i<32;i++) red[tid][i]=0.0f;
  }
  __syncthreads();
  if (tid<32){
    float acc=0.0f;
    for (int t=0;t<256;t++) acc += red[t][tid];
    pp[(size_t)blockIdx.x*32 + tid] = acc;
  }
}

__global__ __launch_bounds__(64) void k_pool_final(
    const float* __restrict__ pp, const float* __restrict__ bsum,
    const float* __restrict__ fcw, const float* __restrict__ fcb,
    float* __restrict__ out)
{
  __shared__ float sp[32];
  const int b = blockIdx.x, tid = threadIdx.x;
  if (tid<32){
    float acc=0.0f;
    for (int ch=0;ch<63;ch++) acc += pp[(size_t)(b*63+ch)*32+tid];
    sp[tid] = acc / bsum[b];
  }
  __syncthreads();
  if (tid<2){
    float v = fcb[tid];
    for (int o=0;o<32;o++) v += sp[o]*fcw[o*2+tid];
    out[b*2+tid]=v;
  }
}

extern "C" void kernel_launch(void* const* d_in, const int* in_sizes, int n_in,
                              void* d_out, int out_size, void* d_ws, size_t ws_size,
                              hipStream_t stream)
{
  const float* x      = (const float*)d_in[0];
  const float* band_w = (const float*)d_in[1];
  const float* pw_w   = (const float*)d_in[2];
  const float* bn_g   = (const float*)d_in[3];
  const float* bn_b   = (const float*)d_in[4];
  const float* bn_m   = (const float*)d_in[5];
  const float* bn_v   = (const float*)d_in[6];
  const float* ln1_g  = (const float*)d_in[7];
  const float* ln1_b  = (const float*)d_in[8];
  const float* wqkv   = (const float*)d_in[9];
  const float* proj   = (const float*)d_in[10];
  const float* wproj  = (const float*)d_in[11];
  const float* bprojp = (const float*)d_in[12];
  const float* ln2_g  = (const float*)d_in[13];
  const float* ln2_b  = (const float*)d_in[14];
  const float* w1     = (const float*)d_in[15];
  const float* b1     = (const float*)d_in[16];
  const float* w2     = (const float*)d_in[17];
  const float* b2     = (const float*)d_in[18];
  const float* norm_g = (const float*)d_in[19];
  const float* norm_b = (const float*)d_in[20];
  const float* pool_w = (const float*)d_in[21];
  const float* pool_b = (const float*)d_in[22];
  const float* fc_w   = (const float*)d_in[23];
  const float* fc_b   = (const float*)d_in[24];
  float* out = (float*)d_out;
  float* ws  = (float*)d_ws;

  float* hbuf  = ws;                       // 8,192,000 floats (32 MB)
  float* kvp   = hbuf + 8192000;           // 2000*2048 = 4,096,000
  float* p2    = kvp  + 4096000;           // 10*2048 = 20,480
  float* KV    = p2   + 20480;             // 2048
  float* sbuf  = KV   + 2048;              // 256,000
  float* bmax  = sbuf + 256000;            // 16
  float* bsum  = bmax + 16;                // 16
  float* pp    = bsum + 16;                // 16*63*32 = 32,256

  k_tokenize<<<1024,256,0,stream>>>(x, band_w, pw_w, bn_g, bn_b, bn_m, bn_v, hbuf);
  for (int l=0;l<2;l++){
    k_kv_partial<<<2000,256,0,stream>>>(hbuf, ln1_g, ln1_b, wqkv, proj, kvp, l);
    k_kv_reduce1<<<80,256,0,stream>>>(kvp, p2);
    k_kv_reduce2<<<1,256,0,stream>>>(p2, KV);
    k_attn<<<500,256,0,stream>>>(hbuf, ln1_g, ln1_b, wqkv, proj, wproj, bprojp, KV, l);
    k_ffn<<<500,256,0,stream>>>(hbuf, ln2_g, ln2_b, w1, b1, w2, b2, l);
  }
  k_pool_score<<<1000,256,0,stream>>>(hbuf, norm_g, norm_b, pool_w, pool_b, sbuf);
  k_softmax_stats<<<16,256,0,stream>>>(sbuf, bmax, bsum);
  k_pool_partial<<<16*63,256,0,stream>>>(hbuf, norm_g, norm_b, sbuf, bmax, pp);
  k_pool_final<<<16,64,0,stream>>>(pp, bsum, fc_w, fc_b, out);
}

// Round 13
// 637.559 us; speedup vs baseline: 1.3819x; 1.0423x over previous
//
#include <hip/hip_runtime.h>
#include <math.h>

#define NTOK   256000
#define TOKB   16000
#define EPS    1e-5f

__device__ __forceinline__ float gelu_f(float x){
  return 0.5f*x*(1.0f+erff(x*0.70710678118654752440f));
}
__device__ __forceinline__ float elu1_f(float x){
  return x>0.0f ? x+1.0f : __expf(x);   // elu(x)+1
}

// ---------------------------------------------------------------------------
// Tokenizer: band conv(51) -> 1x1 conv(4->32) -> BN -> GELU -> avgpool(4)
// ---------------------------------------------------------------------------
__global__ __launch_bounds__(256) void k_tokenize(
    const float* __restrict__ x, const float* __restrict__ band_w,
    const float* __restrict__ pw_w, const float* __restrict__ bn_g,
    const float* __restrict__ bn_b, const float* __restrict__ bn_m,
    const float* __restrict__ bn_v, float* __restrict__ hout)
{
  __shared__ float sx[1050];
  __shared__ float sbw[4][51];
  __shared__ float spw[32][4];
  __shared__ float sscale[32], sshift[32];
  const int tid = threadIdx.x;
  const int b = blockIdx.x >> 6, e = blockIdx.x & 63;
  const float* xr = x + (size_t)(b*64 + e)*1000;
  for (int i=tid;i<1050;i+=256){ int t=i-25; sx[i]=(t>=0&&t<1000)?xr[t]:0.0f; }
  for (int i=tid;i<204;i+=256){ sbw[i/51][i%51] = band_w[i]; }
  for (int i=tid;i<128;i+=256){ spw[i>>2][i&3] = pw_w[i]; }
  if (tid<32){ float sc = bn_g[tid]*rsqrtf(bn_v[tid]+EPS);
               sscale[tid]=sc; sshift[tid]=bn_b[tid]-bn_m[tid]*sc; }
  __syncthreads();
  const int tp = tid;
  if (tp < 250) {
    float acc[32];
    #pragma unroll
    for (int o=0;o<32;o++) acc[o]=0.0f;
    for (int j=0;j<4;j++){
      const int t = 4*tp+j;
      float c0=0,c1=0,c2=0,c3=0;
      for (int k=0;k<51;k++){
        float xv = sx[t+k];
        c0 += xv*sbw[0][k]; c1 += xv*sbw[1][k];
        c2 += xv*sbw[2][k]; c3 += xv*sbw[3][k];
      }
      #pragma unroll
      for (int o=0;o<32;o++){
        float hv = spw[o][0]*c0 + spw[o][1]*c1 + spw[o][2]*c2 + spw[o][3]*c3;
        hv = hv*sscale[o] + sshift[o];
        acc[o] += gelu_f(hv);
      }
    }
    const int tok = b*TOKB + e*250 + tp;
    float4* dst = (float4*)(hout + (size_t)tok*32);
    #pragma unroll
    for (int o8=0;o8<8;o8++)
      dst[o8] = make_float4(acc[o8*4]*0.25f, acc[o8*4+1]*0.25f,
                            acc[o8*4+2]*0.25f, acc[o8*4+3]*0.25f);
  }
}

// ---------------------------------------------------------------------------
// Pass A: per 128-token tile: ln1 -> k,v -> K-features -> partial KV[h,f,d]
// (R7 proven version)
// ---------------------------------------------------------------------------
__global__ __launch_bounds__(256) void k_kv_partial(
    const float* __restrict__ hbuf, const float* __restrict__ ln1_g,
    const float* __restrict__ ln1_b, const float* __restrict__ wqkv,
    const float* __restrict__ proj_mat, float* __restrict__ kvpart, int l)
{
  __shared__ __align__(16) float sk[128][36];
  __shared__ __align__(16) float sv[128][36];
  __shared__ __align__(16) float swkT[64][32];
  __shared__ float sg[32], sb[32];
  const int tid = threadIdx.x;
  const float* W = wqkv + l*32*96;
  for (int idx=tid;idx<2048;idx+=256){
    int i = idx&31, j = idx>>5;
    swkT[j][i] = W[i*96 + 32 + j];
  }
  if (tid<32){ sg[tid]=ln1_g[l*32+tid]; sb[tid]=ln1_b[l*32+tid]; }
  __syncthreads();
  {
    const int tloc = tid>>1, half = tid&1;
    const int tok = blockIdx.x*128 + tloc;
    float hx[32];
    const float4* src = (const float4*)(hbuf + (size_t)tok*32);
    #pragma unroll
    for (int i=0;i<8;i++){ float4 v4=src[i]; hx[4*i]=v4.x; hx[4*i+1]=v4.y; hx[4*i+2]=v4.z; hx[4*i+3]=v4.w; }
    float mu=0;
    #pragma unroll
    for (int i=0;i<32;i++) mu += hx[i];
    mu *= (1.0f/32.0f);
    float vs=0;
    #pragma unroll
    for (int i=0;i<32;i++){ float d=hx[i]-mu; vs += d*d; }
    const float inv = rsqrtf(vs*(1.0f/32.0f)+EPS);
    float xn[32];
    #pragma unroll
    for (int i=0;i<32;i++) xn[i] = (hx[i]-mu)*inv*sg[i]+sb[i];
    const int j0 = half*16;
    #pragma unroll 4
    for (int jj=0;jj<16;jj++){
      const int j = j0+jj;
      const float4* wk4 = (const float4*)&swkT[j][0];
      const float4* wv4 = (const float4*)&swkT[32+j][0];
      float ka=0, va=0;
      #pragma unroll
      for (int i4=0;i4<8;i4++){
        float4 wk = wk4[i4], wv = wv4[i4];
        ka += xn[4*i4+0]*wk.x + xn[4*i4+1]*wk.y + xn[4*i4+2]*wk.z + xn[4*i4+3]*wk.w;
        va += xn[4*i4+0]*wv.x + xn[4*i4+1]*wv.y + xn[4*i4+2]*wv.z + xn[4*i4+3]*wv.w;
      }
      sk[tloc][j]=ka; sv[tloc][j]=va;
    }
  }
  __syncthreads();
  const int hh = tid>>6, f = tid&63;
  float pm0,pm1,pm2,pm3,pm4,pm5,pm6,pm7;
  {
    const float* pmp = proj_mat + ((size_t)(l*4+hh)*8)*64 + f;
    pm0=pmp[0]; pm1=pmp[64]; pm2=pmp[128]; pm3=pmp[192];
    pm4=pmp[256]; pm5=pmp[320]; pm6=pmp[384]; pm7=pmp[448];
  }
  float a0=0,a1=0,a2=0,a3=0,a4=0,a5=0,a6=0,a7=0;
  #pragma unroll 4
  for (int t=0;t<128;t++){
    const float4* k4 = (const float4*)&sk[t][hh*8];
    const float4* v4 = (const float4*)&sv[t][hh*8];
    float4 ka = k4[0], kb = k4[1];
    float kd = ka.x*pm0 + ka.y*pm1 + ka.z*pm2 + ka.w*pm3
             + kb.x*pm4 + kb.y*pm5 + kb.z*pm6 + kb.w*pm7;
    const float Kf = elu1_f(kd);
    float4 va = v4[0], vb = v4[1];
    a0 += Kf*va.x; a1 += Kf*va.y; a2 += Kf*va.z; a3 += Kf*va.w;
    a4 += Kf*vb.x; a5 += Kf*vb.y; a6 += Kf*vb.z; a7 += Kf*vb.w;
  }
  float4* dst = (float4*)(kvpart + (size_t)blockIdx.x*2048 + tid*8);
  dst[0] = make_float4(a0,a1,a2,a3);
  dst[1] = make_float4(a4,a5,a6,a7);
}

// fixed-order hierarchical KV reduction: 2000 partials -> 10 chunks -> final
__global__ __launch_bounds__(256) void k_kv_reduce1(
    const float* __restrict__ kvpart, float* __restrict__ p2)
{
  const int chunk = blockIdx.x >> 3;
  const int e = (blockIdx.x&7)*256 + threadIdx.x;
  float acc=0.0f;
  const int base = chunk*200;
  for (int ab=0; ab<200; ab++) acc += kvpart[(size_t)(base+ab)*2048 + e];
  p2[chunk*2048 + e] = acc;
}

__global__ __launch_bounds__(256) void k_kv_reduce2(
    const float* __restrict__ p2, float* __restrict__ KV)
{
  const int hf = threadIdx.x;
  float acc[8];
  #pragma unroll
  for (int d=0;d<8;d++) acc[d]=0.0f;
  for (int c=0;c<10;c++){
    #pragma unroll
    for (int d=0;d<8;d++) acc[d] += p2[c*2048 + hf*8 + d];
  }
  #pragma unroll
  for (int d=0;d<8;d++) KV[hf*8+d]=acc[d];
}

// ---------------------------------------------------------------------------
// Pass C1: TWO tokens/thread, register-phased; __launch_bounds__(256,2)
// caps the allocator at a 2-waves/EU budget (256 VGPR) so it stops the
// R12 partial spill (48 MB scratch writes at VGPR=144+spill).
// ---------------------------------------------------------------------------
__global__ __launch_bounds__(256,2) void k_attn(
    float* __restrict__ hbuf,
    const float* __restrict__ ln1_g, const float* __restrict__ ln1_b,
    const float* __restrict__ wqkv, const float* __restrict__ proj_mat,
    const float* __restrict__ wproj, const float* __restrict__ bproj,
    const float* __restrict__ KV, int l)
{
  __shared__ __align__(16) float swqT[32][32];   // [j][i]
  __shared__ __align__(16) float spmT[4][64][8]; // [h][f][d]
  __shared__ __align__(16) float sKVT[4][64][8]; // [h][f][d]
  __shared__ __align__(16) float swpT[32][32];   // [o][i]
  __shared__ float s1g[32], s1b[32], sbp[32];
  const int tid = threadIdx.x;
  for (int idx=tid; idx<1024; idx+=256){
    int j=idx>>5, i=idx&31;
    swqT[j][i] = wqkv[l*3072 + i*96 + j];
    swpT[j][i] = wproj[l*1024 + i*32 + j];
  }
  for (int i=tid;i<2048;i+=256){
    int hh=i>>9, f=(i>>3)&63, d=i&7;
    spmT[hh][f][d] = proj_mat[l*2048 + hh*512 + d*64 + f];
    (&sKVT[0][0][0])[i] = KV[i];
  }
  if (tid<32){ s1g[tid]=ln1_g[l*32+tid]; s1b[tid]=ln1_b[l*32+tid];
               sbp[tid]=bproj[l*32+tid]; }
  __syncthreads();

  const int tok0 = blockIdx.x*512 + tid;
  float4* hpA = (float4*)(hbuf + (size_t)tok0*32);
  float4* hpB = hpA + 256*8;          // token tok0+256

  // ---- token A: ln1 -> q (closed scope; xn dies here) ----
  float qA[32];
  {
    float xn[32];
    {
      float hx[32];
      #pragma unroll
      for (int i=0;i<8;i++){ float4 v=hpA[i]; hx[4*i]=v.x; hx[4*i+1]=v.y; hx[4*i+2]=v.z; hx[4*i+3]=v.w; }
      float mu=0;
      #pragma unroll
      for (int i=0;i<32;i++) mu += hx[i];
      mu *= (1.0f/32.0f);
      float vs=0;
      #pragma unroll
      for (int i=0;i<32;i++){ float d=hx[i]-mu; vs += d*d; }
      const float inv = rsqrtf(vs*(1.0f/32.0f)+EPS);
      #pragma unroll
      for (int i=0;i<32;i++) xn[i] = (hx[i]-mu)*inv*s1g[i]+s1b[i];
    }
    #pragma unroll 4
    for (int j=0;j<32;j++){
      const float4* wr = (const float4*)&swqT[j][0];
      float a=0;
      #pragma unroll
      for (int i4=0;i4<8;i4++){
        float4 w = wr[i4];
        a += xn[4*i4+0]*w.x + xn[4*i4+1]*w.y + xn[4*i4+2]*w.z + xn[4*i4+3]*w.w;
      }
      qA[j]=a;
    }
  }
  // ---- token B: ln1 -> q ----
  float qB[32];
  {
    float xn[32];
    {
      float hx[32];
      #pragma unroll
      for (int i=0;i<8;i++){ float4 v=hpB[i]; hx[4*i]=v.x; hx[4*i+1]=v.y; hx[4*i+2]=v.z; hx[4*i+3]=v.w; }
      float mu=0;
      #pragma unroll
      for (int i=0;i<32;i++) mu += hx[i];
      mu *= (1.0f/32.0f);
      float vs=0;
      #pragma unroll
      for (int i=0;i<32;i++){ float d=hx[i]-mu; vs += d*d; }
      const float inv = rsqrtf(vs*(1.0f/32.0f)+EPS);
      #pragma unroll
      for (int i=0;i<32;i++) xn[i] = (hx[i]-mu)*inv*s1g[i]+s1b[i];
    }
    #pragma unroll 4
    for (int j=0;j<32;j++){
      const float4* wr = (const float4*)&swqT[j][0];
      float a=0;
      #pragma unroll
      for (int i4=0;i4<8;i4++){
        float4 w = wr[i4];
        a += xn[4*i4+0]*w.x + xn[4*i4+1]*w.y + xn[4*i4+2]*w.z + xn[4*i4+3]*w.w;
      }
      qB[j]=a;
    }
  }

  // ---- attention per head; token-inner f-loop (weights serve both) ----
  #pragma unroll
  for (int hh=0;hh<4;hh++){
    float aA0=0,aA1=0,aA2=0,aA3=0,aA4=0,aA5=0,aA6=0,aA7=0;
    float aB0=0,aB1=0,aB2=0,aB3=0,aB4=0,aB5=0,aB6=0,aB7=0;
    #pragma unroll 2
    for (int f=0;f<64;f++){
      const float4* pm4 = (const float4*)&spmT[hh][f][0];
      float4 pa = pm4[0], pb = pm4[1];
      float qdA = qA[hh*8+0]*pa.x+qA[hh*8+1]*pa.y+qA[hh*8+2]*pa.z+qA[hh*8+3]*pa.w
                + qA[hh*8+4]*pb.x+qA[hh*8+5]*pb.y+qA[hh*8+6]*pb.z+qA[hh*8+7]*pb.w;
      float qdB = qB[hh*8+0]*pa.x+qB[hh*8+1]*pa.y+qB[hh*8+2]*pa.z+qB[hh*8+3]*pa.w
                + qB[hh*8+4]*pb.x+qB[hh*8+5]*pb.y+qB[hh*8+6]*pb.z+qB[hh*8+7]*pb.w;
      const float QfA = elu1_f(qdA);
      const float QfB = elu1_f(qdB);
      const float4* kv4 = (const float4*)&sKVT[hh][f][0];
      float4 va = kv4[0], vb = kv4[1];
      aA0+=QfA*va.x; aA1+=QfA*va.y; aA2+=QfA*va.z; aA3+=QfA*va.w;
      aA4+=QfA*vb.x; aA5+=QfA*vb.y; aA6+=QfA*vb.z; aA7+=QfA*vb.w;
      aB0+=QfB*va.x; aB1+=QfB*va.y; aB2+=QfB*va.z; aB3+=QfB*va.w;
      aB4+=QfB*vb.x; aB5+=QfB*vb.y; aB6+=QfB*vb.z; aB7+=QfB*vb.w;
    }
    {
      const float z = 1.0f/(aA0+aA1+aA2+aA3+aA4+aA5+aA6+aA7);
      qA[hh*8+0]=aA0*z; qA[hh*8+1]=aA1*z; qA[hh*8+2]=aA2*z; qA[hh*8+3]=aA3*z;
      qA[hh*8+4]=aA4*z; qA[hh*8+5]=aA5*z; qA[hh*8+6]=aA6*z; qA[hh*8+7]=aA7*z;
    }
    {
      const float z = 1.0f/(aB0+aB1+aB2+aB3+aB4+aB5+aB6+aB7);
      qB[hh*8+0]=aB0*z; qB[hh*8+1]=aB1*z; qB[hh*8+2]=aB2*z; qB[hh*8+3]=aB3*z;
      qB[hh*8+4]=aB4*z; qB[hh*8+5]=aB5*z; qB[hh*8+6]=aB6*z; qB[hh*8+7]=aB7*z;
    }
  }

  // ---- proj + residual for both tokens (token-inner) ----
  #pragma unroll 2
  for (int o4=0;o4<8;o4++){
    float pA0=sbp[4*o4+0], pA1=sbp[4*o4+1], pA2=sbp[4*o4+2], pA3=sbp[4*o4+3];
    float pB0=pA0, pB1=pA1, pB2=pA2, pB3=pA3;
    const float4* w0 = (const float4*)&swpT[o4*4+0][0];
    const float4* w1r= (const float4*)&swpT[o4*4+1][0];
    const float4* w2r= (const float4*)&swpT[o4*4+2][0];
    const float4* w3 = (const float4*)&swpT[o4*4+3][0];
    #pragma unroll
    for (int i4=0;i4<8;i4++){
      float4 b0=w0[i4], b1=w1r[i4], b2=w2r[i4], b3=w3[i4];
      pA0 += qA[4*i4+0]*b0.x + qA[4*i4+1]*b0.y + qA[4*i4+2]*b0.z + qA[4*i4+3]*b0.w;
      pA1 += qA[4*i4+0]*b1.x + qA[4*i4+1]*b1.y + qA[4*i4+2]*b1.z + qA[4*i4+3]*b1.w;
      pA2 += qA[4*i4+0]*b2.x + qA[4*i4+1]*b2.y + qA[4*i4+2]*b2.z + qA[4*i4+3]*b2.w;
      pA3 += qA[4*i4+0]*b3.x + qA[4*i4+1]*b3.y + qA[4*i4+2]*b3.z + qA[4*i4+3]*b3.w;
      pB0 += qB[4*i4+0]*b0.x + qB[4*i4+1]*b0.y + qB[4*i4+2]*b0.z + qB[4*i4+3]*b0.w;
      pB1 += qB[4*i4+0]*b1.x + qB[4*i4+1]*b1.y + qB[4*i4+2]*b1.z + qB[4*i4+3]*b1.w;
      pB2 += qB[4*i4+0]*b2.x + qB[4*i4+1]*b2.y + qB[4*i4+2]*b2.z + qB[4*i4+3]*b2.w;
      pB3 += qB[4*i4+0]*b3.x + qB[4*i4+1]*b3.y + qB[4*i4+2]*b3.z + qB[4*i4+3]*b3.w;
    }
    float4 hA = hpA[o4];
    hpA[o4] = make_float4(hA.x+pA0, hA.y+pA1, hA.z+pA2, hA.w+pA3);
    float4 hB = hpB[o4];
    hpB[o4] = make_float4(hB.x+pB0, hB.y+pB1, hB.z+pB2, hB.w+pB3);
  }
}

// ---------------------------------------------------------------------------
// Pass C2: thread handles TWO tokens (R10/R12, works). ln2 -> FFN -> residual.
// ---------------------------------------------------------------------------
__global__ __launch_bounds__(256) void k_ffn(
    float* __restrict__ hbuf,
    const float* __restrict__ ln2_g, const float* __restrict__ ln2_b,
    const float* __restrict__ w1, const float* __restrict__ b1,
    const float* __restrict__ w2, const float* __restrict__ b2, int l)
{
  __shared__ __align__(16) float w1T[64][32];   // [j][i]
  __shared__ __align__(16) float sw2[64][32];   // [j][c]
  __shared__ float s2g[32],s2b[32],sb1[64],sb2[32];
  const int tid = threadIdx.x;
  for (int idx=tid;idx<2048;idx+=256){
    int j=idx>>5, i=idx&31;
    w1T[j][i] = w1[l*2048 + i*64 + j];
    (&sw2[0][0])[idx] = w2[l*2048 + idx];
  }
  if (tid<32){ s2g[tid]=ln2_g[l*32+tid]; s2b[tid]=ln2_b[l*32+tid];
               sb2[tid]=b2[l*32+tid]; }
  if (tid<64) sb1[tid]=b1[l*64+tid];
  __syncthreads();

  const int tok0 = blockIdx.x*512 + tid;
  float4* hpA = (float4*)(hbuf + (size_t)tok0*32);
  float4* hpB = hpA + 256*8;

  float mA[32], mB[32];
  {
    float hx[32];
    #pragma unroll
    for (int i=0;i<8;i++){ float4 v=hpA[i]; hx[4*i]=v.x; hx[4*i+1]=v.y; hx[4*i+2]=v.z; hx[4*i+3]=v.w; }
    float mu=0;
    #pragma unroll
    for (int i=0;i<32;i++) mu += hx[i];
    mu *= (1.0f/32.0f);
    float vs=0;
    #pragma unroll
    for (int i=0;i<32;i++){ float d=hx[i]-mu; vs += d*d; }
    const float inv = rsqrtf(vs*(1.0f/32.0f)+EPS);
    #pragma unroll
    for (int i=0;i<32;i++) mA[i] = (hx[i]-mu)*inv*s2g[i]+s2b[i];
  }
  {
    float hx[32];
    #pragma unroll
    for (int i=0;i<8;i++){ float4 v=hpB[i]; hx[4*i]=v.x; hx[4*i+1]=v.y; hx[4*i+2]=v.z; hx[4*i+3]=v.w; }
    float mu=0;
    #pragma unroll
    for (int i=0;i<32;i++) mu += hx[i];
    mu *= (1.0f/32.0f);
    float vs=0;
    #pragma unroll
    for (int i=0;i<32;i++){ float d=hx[i]-mu; vs += d*d; }
    const float inv = rsqrtf(vs*(1.0f/32.0f)+EPS);
    #pragma unroll
    for (int i=0;i<32;i++) mB[i] = (hx[i]-mu)*inv*s2g[i]+s2b[i];
  }

  float fA[32], fB[32];
  #pragma unroll
  for (int c=0;c<32;c++){ fA[c]=sb2[c]; fB[c]=sb2[c]; }

  #pragma unroll 2
  for (int j=0;j<64;j++){
    const float4* r1 = (const float4*)&w1T[j][0];
    float gA = sb1[j], gB = sb1[j];
    #pragma unroll
    for (int i4=0;i4<8;i4++){
      float4 w = r1[i4];
      gA += mA[4*i4+0]*w.x + mA[4*i4+1]*w.y + mA[4*i4+2]*w.z + mA[4*i4+3]*w.w;
      gB += mB[4*i4+0]*w.x + mB[4*i4+1]*w.y + mB[4*i4+2]*w.z + mB[4*i4+3]*w.w;
    }
    const float ggA = gelu_f(gA);
    const float ggB = gelu_f(gB);
    const float4* r2 = (const float4*)&sw2[j][0];
    #pragma unroll
    for (int c4=0;c4<8;c4++){
      float4 w = r2[c4];
      fA[4*c4+0] += ggA*w.x; fA[4*c4+1] += ggA*w.y; fA[4*c4+2] += ggA*w.z; fA[4*c4+3] += ggA*w.w;
      fB[4*c4+0] += ggB*w.x; fB[4*c4+1] += ggB*w.y; fB[4*c4+2] += ggB*w.z; fB[4*c4+3] += ggB*w.w;
    }
  }

  #pragma unroll
  for (int o4=0;o4<8;o4++){
    float4 hA = hpA[o4];
    hpA[o4] = make_float4(hA.x+fA[4*o4+0], hA.y+fA[4*o4+1],
                          hA.z+fA[4*o4+2], hA.w+fA[4*o4+3]);
    float4 hB = hpB[o4];
    hpB[o4] = make_float4(hB.x+fB[4*o4+0], hB.y+fB[4*o4+1],
                          hB.z+fB[4*o4+2], hB.w+fB[4*o4+3]);
  }
}

// ---------------------------------------------------------------------------
// Final: layernorm -> pool score s; softmax over N per batch; weighted sum; fc
// ---------------------------------------------------------------------------
__global__ __launch_bounds__(256) void k_pool_score(
    const float* __restrict__ hbuf, const float* __restrict__ ng,
    const float* __restrict__ nb, const float* __restrict__ pw,
    const float* __restrict__ pb, float* __restrict__ s)
{
  const int tok = blockIdx.x*256 + threadIdx.x;
  float hx[32];
  const float4* src = (const float4*)(hbuf + (size_t)tok*32);
  #pragma unroll
  for (int i=0;i<8;i++){ float4 v4=src[i]; hx[4*i]=v4.x; hx[4*i+1]=v4.y; hx[4*i+2]=v4.z; hx[4*i+3]=v4.w; }
  float mu=0;
  #pragma unroll
  for (int i=0;i<32;i++) mu += hx[i];
  mu *= (1.0f/32.0f);
  float vs=0;
  #pragma unroll
  for (int i=0;i<32;i++){ float d=hx[i]-mu; vs += d*d; }
  const float inv = rsqrtf(vs*(1.0f/32.0f)+EPS);
  float sv = pb[0];
  #pragma unroll
  for (int i=0;i<32;i++) sv += ((hx[i]-mu)*inv*ng[i]+nb[i])*pw[i];
  s[tok]=sv;
}

__global__ __launch_bounds__(256) void k_softmax_stats(
    const float* __restrict__ s, float* __restrict__ bmax, float* __restrict__ bsum)
{
  __shared__ float red[256];
  __shared__ float smax_sh;
  const int b = blockIdx.x, tid = threadIdx.x;
  const float* sbp = s + (size_t)b*TOKB;
  float mx = -INFINITY;
  for (int i=tid;i<TOKB;i+=256) mx = fmaxf(mx, sbp[i]);
  red[tid]=mx; __syncthreads();
  for (int st=128;st>0;st>>=1){ if(tid<st) red[tid]=fmaxf(red[tid],red[tid+st]); __syncthreads(); }
  if (tid==0) smax_sh = red[0];
  __syncthreads();
  const float smax = smax_sh;
  float acc=0.0f;
  for (int i=tid;i<TOKB;i+=256) acc += __expf(sbp[i]-smax);
  __syncthreads();
  red[tid]=acc; __syncthreads();
  for (int st=128;st>0;st>>=1){ if(tid<st) red[tid]+=red[tid+st]; __syncthreads(); }
  if (tid==0){ bmax[b]=smax; bsum[b]=red[0]; }
}

__global__ __launch_bounds__(256) void k_pool_partial(
    const float* __restrict__ hbuf, const float* __restrict__ ng,
    const float* __restrict__ nb, const float* __restrict__ s,
    const float* __restrict__ bmax, float* __restrict__ pp)
{
  __shared__ float red[256][33];
  const int b = blockIdx.x/63, ch = blockIdx.x%63;
  const int tid = threadIdx.x;
  const int n = ch*256+tid;
  if (n < TOKB) {
    const int tok = b*TOKB+n;
    float hx[32];
    const float4* src = (const float4*)(hbuf + (size_t)tok*32);
    #pragma unroll
    for (int i=0;i<8;i++){ float4 v4=src[i]; hx[4*i]=v4.x; hx[4*i+1]=v4.y; hx[4*i+2]=v4.z; hx[4*i+3]=v4.w; }
    float mu=0;
    #pragma unroll
    for (int i=0;i<32;i++) mu += hx[i];
    mu *= (1.0f/32.0f);
    float vs=0;
    #pragma unroll
    for (int i=0;i<32;i++){ float d=hx[i]-mu; vs += d*d; }
    const float inv = rsqrtf(vs*(1.0f/32.0f)+EPS);
    const float w = __expf(s[tok]-bmax[b]);
    #pragma unroll
    for (int i=0;i<32;i++) red[tid][i] = w*((hx[i]-mu)*inv*ng[i]+nb[i]);
  } else {
    #pragma unroll
    for (int i=0;i<32;i++) red[tid][i]=0.0f;
  }
  __syncthreads();
  if (tid<32){
    float acc=0.0f;
    for (int t=0;t<256;t++) acc += red[t][tid];
    pp[(size_t)blockIdx.x*32 + tid] = acc;
  }
}

__global__ __launch_bounds__(64) void k_pool_final(
    const float* __restrict__ pp, const float* __restrict__ bsum,
    const float* __restrict__ fcw, const float* __restrict__ fcb,
    float* __restrict__ out)
{
  __shared__ float sp[32];
  const int b = blockIdx.x, tid = threadIdx.x;
  if (tid<32){
    float acc=0.0f;
    for (int ch=0;ch<63;ch++) acc += pp[(size_t)(b*63+ch)*32+tid];
    sp[tid] = acc / bsum[b];
  }
  __syncthreads();
  if (tid<2){
    float v = fcb[tid];
    for (int o=0;o<32;o++) v += sp[o]*fcw[o*2+tid];
    out[b*2+tid]=v;
  }
}

extern "C" void kernel_launch(void* const* d_in, const int* in_sizes, int n_in,
                              void* d_out, int out_size, void* d_ws, size_t ws_size,
                              hipStream_t stream)
{
  const float* x      = (const float*)d_in[0];
  const float* band_w = (const float*)d_in[1];
  const float* pw_w   = (const float*)d_in[2];
  const float* bn_g   = (const float*)d_in[3];
  const float* bn_b   = (const float*)d_in[4];
  const float* bn_m   = (const float*)d_in[5];
  const float* bn_v   = (const float*)d_in[6];
  const float* ln1_g  = (const float*)d_in[7];
  const float* ln1_b  = (const float*)d_in[8];
  const float* wqkv   = (const float*)d_in[9];
  const float* proj   = (const float*)d_in[10];
  const float* wproj  = (const float*)d_in[11];
  const float* bprojp = (const float*)d_in[12];
  const float* ln2_g  = (const float*)d_in[13];
  const float* ln2_b  = (const float*)d_in[14];
  const float* w1     = (const float*)d_in[15];
  const float* b1     = (const float*)d_in[16];
  const float* w2     = (const float*)d_in[17];
  const float* b2     = (const float*)d_in[18];
  const float* norm_g = (const float*)d_in[19];
  const float* norm_b = (const float*)d_in[20];
  const float* pool_w = (const float*)d_in[21];
  const float* pool_b = (const float*)d_in[22];
  const float* fc_w   = (const float*)d_in[23];
  const float* fc_b   = (const float*)d_in[24];
  float* out = (float*)d_out;
  float* ws  = (float*)d_ws;

  float* hbuf  = ws;                       // 8,192,000 floats (32 MB)
  float* kvp   = hbuf + 8192000;           // 2000*2048 = 4,096,000
  float* p2    = kvp  + 4096000;           // 10*2048 = 20,480
  float* KV    = p2   + 20480;             // 2048
  float* sbuf  = KV   + 2048;              // 256,000
  float* bmax  = sbuf + 256000;            // 16
  float* bsum  = bmax + 16;                // 16
  float* pp    = bsum + 16;                // 16*63*32 = 32,256

  k_tokenize<<<1024,256,0,stream>>>(x, band_w, pw_w, bn_g, bn_b, bn_m, bn_v, hbuf);
  for (int l=0;l<2;l++){
    k_kv_partial<<<2000,256,0,stream>>>(hbuf, ln1_g, ln1_b, wqkv, proj, kvp, l);
    k_kv_reduce1<<<80,256,0,stream>>>(kvp, p2);
    k_kv_reduce2<<<1,256,0,stream>>>(p2, KV);
    k_attn<<<500,256,0,stream>>>(hbuf, ln1_g, ln1_b, wqkv, proj, wproj, bprojp, KV, l);
    k_ffn<<<500,256,0,stream>>>(hbuf, ln2_g, ln2_b, w1, b1, w2, b2, l);
  }
  k_pool_score<<<1000,256,0,stream>>>(hbuf, norm_g, norm_b, pool_w, pool_b, sbuf);
  k_softmax_stats<<<16,256,0,stream>>>(sbuf, bmax, bsum);
  k_pool_partial<<<16*63,256,0,stream>>>(hbuf, norm_g, norm_b, sbuf, bmax, pp);
  k_pool_final<<<16,64,0,stream>>>(pp, bsum, fc_w, fc_b, out);
}